// Round 12
// baseline (915.821 us; speedup 1.0000x reference)
//
#include <hip/hip_runtime.h>
#include <cstdint>

typedef unsigned short ushort_t;
typedef _Float16 half_t;
typedef __attribute__((ext_vector_type(8))) short short8;
typedef __attribute__((ext_vector_type(8))) half_t half8;
typedef __attribute__((ext_vector_type(4))) half_t half4;
typedef __attribute__((ext_vector_type(4))) float f32x4;

// ---------------- helpers ----------------
__device__ __forceinline__ void gld_lds16(const ushort_t* g, ushort_t* l) {
    __builtin_amdgcn_global_load_lds((const __attribute__((address_space(1))) void*)g,
                                     (__attribute__((address_space(3))) void*)l,
                                     16, 0, 0);
}

// ---------------- expand: X fp32 [N][IN] -> E fp16 [N][9][IN] ----------------
template<int IN>
__global__ void expand_kernel(const float* __restrict__ X, half_t* __restrict__ E, int nrows) {
    int idx = blockIdx.x * 256 + threadIdx.x;
    if (idx >= nrows * IN) return;
    int n = idx / IN, i = idx % IN;
    float x = X[idx];
    float si = x / (1.0f + __expf(-x));
    float u = (x + 2.2f) * 2.5f;
    int ji = (int)floorf(u);
    float f = u - (float)ji;
    if (!(ji >= 0 && ji <= 10)) ji = -100;      // outside knot range -> all bases 0
    float f2 = f * f, f3 = f2 * f;
    float w_i   = f3 * (1.0f / 6.0f);
    float w_im1 = (1.0f + 3.0f * f + 3.0f * f2 - 3.0f * f3) * (1.0f/6.0f);
    float w_im2 = (4.0f - 6.0f * f2 + 3.0f * f3) * (1.0f/6.0f);
    float omf = 1.0f - f;
    float w_im3 = omf * omf * omf * (1.0f / 6.0f);
    half_t* Er = E + (long)n * 9 * IN + i;
    Er[0] = (half_t)si;
    #pragma unroll
    for (int c = 0; c < 8; ++c) {
        float v = 0.0f;
        v = (c == ji    ) ? w_i   : v;
        v = (c == ji - 1) ? w_im1 : v;
        v = (c == ji - 2) ? w_im2 : v;
        v = (c == ji - 3) ? w_im3 : v;
        Er[(long)(c + 1) * IN] = (half_t)v;
    }
}

// ---------------- pack weights hi/lo ----------------
template<int IN>
__global__ void pack_kernel(const float* __restrict__ base, const float* __restrict__ spline,
                            half_t* __restrict__ Whi, half_t* __restrict__ Wlo, int nout) {
    int idx = blockIdx.x * 256 + threadIdx.x;
    if (idx >= nout * IN) return;
    int o = idx / IN, i = idx % IN;
    long r0 = (long)o * 9 * IN + i;
    float w[9];
    w[0] = base[idx];
    const f32x4* sp = (const f32x4*)(spline + (long)idx * 8);
    f32x4 s0 = sp[0], s1 = sp[1];
    w[1] = s0[0]; w[2] = s0[1]; w[3] = s0[2]; w[4] = s0[3];
    w[5] = s1[0]; w[6] = s1[1]; w[7] = s1[2]; w[8] = s1[3];
    #pragma unroll
    for (int c = 0; c < 9; ++c) {
        half_t hi = (half_t)w[c];
        half_t lo = (half_t)(w[c] - (float)hi);
        Whi[r0 + (long)c * IN] = hi;
        Wlo[r0 + (long)c * IN] = lo;
    }
}

enum { EPI_PART = 0, EPI_QKV = 1, EPI_SH = 2, EPI_PV = 3, EPI_RELU = 4 };

// ---------------- pipelined GEMM: 128x128 block, 2 waves of 128x64, BK=32 ----------------
// 3-slot LDS (48 KB -> 3 blocks/CU), counted vmcnt(8), swizzle s(row)=(row>>1)&3
// (r10-verified conflict-free, both sides). 12 LDS reads -> 32 MFMA per wave-step.
// All grids are exact multiples of 256*blocks/CU -> no dispatch-round quantization.
// Virtual 2*NT K-tiles (hi then lo). EPI_QKV: stripes bn<1024 (Q,K) run hi-only.
template<int EPI, int KSPLIT>
__global__ __launch_bounds__(128, 2)
void gemm_s(const ushort_t* __restrict__ A, const ushort_t* __restrict__ Bhi,
            const ushort_t* __restrict__ Blo, float* __restrict__ Cf, float* __restrict__ P,
            half_t* __restrict__ Qp, half_t* __restrict__ Kp, half_t* __restrict__ Vp,
            int M, int N, int K) {
    constexpr int SLOT = 128 * 32;
    __shared__ __attribute__((aligned(16))) ushort_t lds[6 * SLOT];   // A: 0..3, B: 3..6 (48 KB)
    const int tid = threadIdx.x;
    const int lane = tid & 63;
    const int wn = tid >> 6;                    // 2 waves: wave-tile 128x64
    const int l15 = lane & 15, l16 = lane >> 4;
    const int bm = blockIdx.x * 128, bn = blockIdx.y * 128;
    const int NT = K >> 5;
    int kc, t0;
    if constexpr (KSPLIT > 1) { kc = (2 * NT) / KSPLIT; t0 = blockIdx.z * kc; }
    else { kc = (EPI == EPI_QKV && bn < 1024) ? NT : 2 * NT; t0 = 0; }

    auto stage = [&](int tt, int s) {
        int pass = (tt >= NT) ? 1 : 0;
        int kt = (tt - (pass ? NT : 0)) << 5;
        const ushort_t* Bb = pass ? Blo : Bhi;
        ushort_t* sA = &lds[s * SLOT];
        ushort_t* sB = &lds[(3 + s) * SLOT];
        #pragma unroll
        for (int r = 0; r < 4; ++r) {           // A: 128x32 = 512 chunks, 4/thread
            int ch = r * 128 + tid;
            int row = ch >> 2, c = ch & 3;
            gld_lds16(A + (long)(bm + row) * K + kt + ((c ^ ((row >> 1) & 3)) << 3), sA + ch * 8);
        }
        #pragma unroll
        for (int r = 0; r < 4; ++r) {           // B: 128x32 = 512 chunks, 4/thread
            int ch = r * 128 + tid;
            int row = ch >> 2, c = ch & 3;
            gld_lds16(Bb + (long)(bn + row) * K + kt + ((c ^ ((row >> 1) & 3)) << 3), sB + ch * 8);
        }
    };

    f32x4 acc[8][4];
    #pragma unroll
    for (int m = 0; m < 8; ++m)
        #pragma unroll
        for (int n = 0; n < 4; ++n) acc[m][n] = (f32x4){0.f, 0.f, 0.f, 0.f};

    stage(t0, 0);
    stage(t0 + 1, 1);
    asm volatile("s_waitcnt vmcnt(8)" ::: "memory");   // tile t0's 8 loads landed
    __builtin_amdgcn_s_barrier();
    __builtin_amdgcn_sched_barrier(0);

    for (int u = 0; u < kc; ++u) {
        int s = u % 3;
        const ushort_t* sA = &lds[s * SLOT];
        const ushort_t* sB = &lds[(3 + s) * SLOT];
        half8 af[8], bf[4];
        #pragma unroll
        for (int mf = 0; mf < 8; ++mf) {
            int row = mf * 16 + l15;
            af[mf] = __builtin_bit_cast(half8, *(const short8*)&sA[row * 32 + ((l16 ^ ((row >> 1) & 3)) << 3)]);
        }
        #pragma unroll
        for (int nf = 0; nf < 4; ++nf) {
            int row = wn * 64 + nf * 16 + l15;
            bf[nf] = __builtin_bit_cast(half8, *(const short8*)&sB[row * 32 + ((l16 ^ ((row >> 1) & 3)) << 3)]);
        }
        __builtin_amdgcn_s_setprio(1);
        #pragma unroll
        for (int mf = 0; mf < 8; ++mf)
            #pragma unroll
            for (int nf = 0; nf < 4; ++nf)
                acc[mf][nf] = __builtin_amdgcn_mfma_f32_16x16x32_f16(af[mf], bf[nf], acc[mf][nf], 0, 0, 0);
        __builtin_amdgcn_s_setprio(0);
        if (u + 2 < kc) {
            stage(t0 + u + 2, (u + 2) % 3);      // slot (u-1)%3: its readers passed last barrier
            asm volatile("s_waitcnt vmcnt(8)" ::: "memory");   // tile u+1 landed, u+2 in flight
        } else {
            asm volatile("s_waitcnt vmcnt(0)" ::: "memory");   // tail drain (last 2 iters)
        }
        __builtin_amdgcn_s_barrier();
        __builtin_amdgcn_sched_barrier(0);
    }

    // epilogue: C/D layout col=lane&15, row=(lane>>4)*4+j (m89-verified)
    #pragma unroll
    for (int mf = 0; mf < 8; ++mf) {
        #pragma unroll
        for (int nf = 0; nf < 4; ++nf) {
            #pragma unroll
            for (int j = 0; j < 4; ++j) {
                int row = bm + mf * 16 + l16 * 4 + j;
                int col = bn + wn * 64 + nf * 16 + l15;
                float v = acc[mf][nf][j];
                if constexpr (KSPLIT > 1) {
                    P[(size_t)blockIdx.z * M * N + (long)row * N + col] = v;
                } else if constexpr (EPI == EPI_RELU) {
                    Cf[(long)row * N + col] = fmaxf(v, 0.0f);
                } else if constexpr (EPI == EPI_QKV) {
                    int which = col >> 9, w5 = col & 511, h = w5 >> 7, d = w5 & 127;
                    int b = row >> 10, ss = row & 1023;
                    half_t* dst = (which == 0) ? Qp : ((which == 1) ? Kp : Vp);
                    dst[(((long)(b * 4 + h) * 1024 + ss) << 7) + d] = (half_t)v;
                }
            }
        }
    }
}

// ---------------- legacy 128x128 GEMM (attention: S-half and PV) ----------------
template<int EPI>
__global__ void gemm_t(const ushort_t* __restrict__ A, const ushort_t* __restrict__ B,
                       float* __restrict__ Cf, half_t* __restrict__ Sh,
                       int M, int N, int K, long sA, long sB, long sC, float scale) {
    __shared__ ushort_t As[128 * 64];
    __shared__ ushort_t Bs[128 * 64];
    const int tid = threadIdx.x;
    const int lane = tid & 63;
    const int wave = tid >> 6;
    const int wm = wave >> 1, wn = wave & 1;
    const int bm = blockIdx.x * 128, bn = blockIdx.y * 128;
    const int z = blockIdx.z;
    const int l15 = lane & 15, l16 = lane >> 4;
    const ushort_t* Ab = A + (long)z * sA;
    const ushort_t* Bb = B + (long)z * sB;

    f32x4 acc[4][4];
    #pragma unroll
    for (int m = 0; m < 4; ++m)
        #pragma unroll
        for (int n = 0; n < 4; ++n) acc[m][n] = (f32x4){0.f, 0.f, 0.f, 0.f};

    for (int kt = 0; kt < K; kt += 64) {
        #pragma unroll
        for (int r = 0; r < 4; ++r) {
            int chunk = r * 256 + tid;
            gld_lds16(Ab + (long)(bm + (chunk >> 3)) * K + kt + ((chunk & 7) << 3), &As[chunk * 8]);
        }
        #pragma unroll
        for (int r = 0; r < 4; ++r) {
            int chunk = r * 256 + tid;
            gld_lds16(Bb + (long)(bn + (chunk >> 3)) * K + kt + ((chunk & 7) << 3), &Bs[chunk * 8]);
        }
        __syncthreads();
        #pragma unroll
        for (int kk = 0; kk < 2; ++kk) {
            half8 af[4], bfr[4];
            #pragma unroll
            for (int m = 0; m < 4; ++m)
                af[m] = __builtin_bit_cast(half8, *(const short8*)&As[(wm * 64 + m * 16 + l15) * 64 + kk * 32 + l16 * 8]);
            #pragma unroll
            for (int n = 0; n < 4; ++n)
                bfr[n] = __builtin_bit_cast(half8, *(const short8*)&Bs[(wn * 64 + n * 16 + l15) * 64 + kk * 32 + l16 * 8]);
            #pragma unroll
            for (int m = 0; m < 4; ++m)
                #pragma unroll
                for (int n = 0; n < 4; ++n)
                    acc[m][n] = __builtin_amdgcn_mfma_f32_16x16x32_f16(af[m], bfr[n], acc[m][n], 0, 0, 0);
        }
        __syncthreads();
    }

    #pragma unroll
    for (int m = 0; m < 4; ++m) {
        #pragma unroll
        for (int n = 0; n < 4; ++n) {
            #pragma unroll
            for (int j = 0; j < 4; ++j) {
                int row = bm + wm * 64 + m * 16 + l16 * 4 + j;
                int col = bn + wn * 64 + n * 16 + l15;
                float v = acc[m][n][j];
                if constexpr (EPI == EPI_SH) {
                    Sh[(long)z * sC + (long)row * N + col] = (half_t)(v * scale);
                } else if constexpr (EPI == EPI_PV) {
                    int b = z >> 2, h = z & 3;
                    Cf[((long)(b * 1024 + row) * 512) + h * 128 + col] = v;
                }
            }
        }
    }
}

// ---------------- split-K reduction ----------------
template<int KS, bool RELU>
__global__ void reduce_kernel(const float* __restrict__ P, float* __restrict__ out, long MN) {
    long i = ((long)blockIdx.x * 256 + threadIdx.x) * 4;
    if (i >= MN) return;
    f32x4 s = *(const f32x4*)&P[i];
    #pragma unroll
    for (int zz = 1; zz < KS; ++zz) {
        f32x4 t = *(const f32x4*)&P[(size_t)zz * MN + i];
        s += t;
    }
    if constexpr (RELU) {
        s[0] = fmaxf(s[0], 0.f); s[1] = fmaxf(s[1], 0.f);
        s[2] = fmaxf(s[2], 0.f); s[3] = fmaxf(s[3], 0.f);
    }
    *(f32x4*)&out[i] = s;
}

// ---------------- V transpose ----------------
__global__ void transpose_v(const ushort_t* __restrict__ V, ushort_t* __restrict__ Vt) {
    __shared__ ushort_t t[64][72];
    int s0 = blockIdx.x * 64, d0 = blockIdx.y * 64, bh = blockIdx.z;
    const ushort_t* Vb = V + (long)bh * 1024 * 128;
    ushort_t* Vtb = Vt + (long)bh * 128 * 1024;
    int tid = threadIdx.x;
    int r = tid >> 2, g = tid & 3;
    #pragma unroll
    for (int j = 0; j < 16; ++j)
        t[r][g * 16 + j] = Vb[(long)(s0 + r) * 128 + d0 + g * 16 + j];
    __syncthreads();
    #pragma unroll
    for (int j = 0; j < 16; ++j)
        Vtb[(long)(d0 + r) * 1024 + s0 + g * 16 + j] = t[g * 16 + j][r];
}

// ---------------- softmax over rows of 1024, fp16, in-place safe (row-local) ----------------
__global__ void softmax_kernel(const half_t* __restrict__ S, half_t* __restrict__ P) {
    long row = (long)blockIdx.x * 4 + (threadIdx.x >> 6);
    int lane = threadIdx.x & 63;
    const half_t* Sr = S + row * 1024;
    float f[16];
    #pragma unroll
    for (int c = 0; c < 2; ++c) {
        half8 h = *(const half8*)&Sr[c * 512 + lane * 8];
        #pragma unroll
        for (int j = 0; j < 8; ++j) f[c * 8 + j] = (float)h[j];
    }
    float mx = -3.0e38f;
    #pragma unroll
    for (int j = 0; j < 16; ++j) mx = fmaxf(mx, f[j]);
    #pragma unroll
    for (int off = 32; off > 0; off >>= 1) mx = fmaxf(mx, __shfl_xor(mx, off));
    float sum = 0.0f;
    #pragma unroll
    for (int j = 0; j < 16; ++j) { f[j] = __expf(f[j] - mx); sum += f[j]; }
    #pragma unroll
    for (int off = 32; off > 0; off >>= 1) sum += __shfl_xor(sum, off);
    float inv = 1.0f / sum;
    half_t* Pr = P + row * 1024;
    #pragma unroll
    for (int c = 0; c < 2; ++c) {
        half8 o;
        #pragma unroll
        for (int j = 0; j < 8; ++j) o[j] = (half_t)(f[c * 8 + j] * inv);
        *(half8*)&Pr[c * 512 + lane * 8] = o;
    }
}

// ---------------- residual + LayerNorm ----------------
__global__ void ln_kernel(const float* __restrict__ O, const float* __restrict__ X,
                          const float* __restrict__ g, const float* __restrict__ b,
                          float* __restrict__ out) {
    long row = (long)blockIdx.x * 4 + (threadIdx.x >> 6);
    int lane = threadIdx.x & 63;
    long base = row * 512 + lane * 8;
    f32x4 o0 = *(const f32x4*)&O[base], o1 = *(const f32x4*)&O[base + 4];
    f32x4 x0 = *(const f32x4*)&X[base], x1 = *(const f32x4*)&X[base + 4];
    float y[8];
    #pragma unroll
    for (int j = 0; j < 4; ++j) { y[j] = o0[j] + x0[j]; y[j + 4] = o1[j] + x1[j]; }
    float s = 0.f;
    #pragma unroll
    for (int j = 0; j < 8; ++j) s += y[j];
    #pragma unroll
    for (int off = 32; off > 0; off >>= 1) s += __shfl_xor(s, off);
    float mu = s * (1.0f / 512.0f);
    float vs = 0.f;
    #pragma unroll
    for (int j = 0; j < 8; ++j) { float d = y[j] - mu; vs += d * d; }
    #pragma unroll
    for (int off = 32; off > 0; off >>= 1) vs += __shfl_xor(vs, off);
    float r = rsqrtf(vs * (1.0f / 512.0f) + 1e-5f);
    f32x4 w0 = *(const f32x4*)&g[lane * 8], w1 = *(const f32x4*)&g[lane * 8 + 4];
    f32x4 b0 = *(const f32x4*)&b[lane * 8], b1 = *(const f32x4*)&b[lane * 8 + 4];
    f32x4 r0, r1;
    #pragma unroll
    for (int j = 0; j < 4; ++j) {
        r0[j] = (y[j] - mu) * r * w0[j] + b0[j];
        r1[j] = (y[j + 4] - mu) * r * w1[j] + b1[j];
    }
    *(f32x4*)&out[base] = r0;
    *(f32x4*)&out[base + 4] = r1;
}

// ---------------- launch ----------------
extern "C" void kernel_launch(void* const* d_in, const int* in_sizes, int n_in,
                              void* d_out, int out_size, void* d_ws, size_t ws_size,
                              hipStream_t stream) {
    const float* x         = (const float*)d_in[0];
    const float* k1_base   = (const float*)d_in[1];
    const float* k1_spline = (const float*)d_in[2];
    const float* k2_base   = (const float*)d_in[3];
    const float* k2_spline = (const float*)d_in[4];
    const float* q_base    = (const float*)d_in[5];
    const float* q_spline  = (const float*)d_in[6];
    const float* k_base    = (const float*)d_in[7];
    const float* k_spline  = (const float*)d_in[8];
    const float* v_base    = (const float*)d_in[9];
    const float* v_spline  = (const float*)d_in[10];
    const float* o_base    = (const float*)d_in[11];
    const float* o_spline  = (const float*)d_in[12];
    const float* ln_w      = (const float*)d_in[13];
    const float* ln_b      = (const float*)d_in[14];
    float* out = (float*)d_out;

    constexpr int Dm = 512, HD = 1024, NR = 8192;
    constexpr int K1 = 9 * Dm;   // 4608
    constexpr int K2 = 9 * HD;   // 9216
    constexpr long SQ = (long)1024 * 128;
    constexpr long SS = (long)1024 * 1024;
    constexpr size_t MB = 1024 * 1024;

    char* p = (char*)d_ws;
    size_t off = 0;
    auto take = [&](size_t bytes) -> char* {
        char* r = p + off;
        off += (bytes + 255) & ~(size_t)255;
        return r;
    };
    half_t* W1hi = (half_t*)take((size_t)HD * K1 * 2);
    half_t* W2hi = (half_t*)take((size_t)Dm * K2 * 2);
    half_t* Wqhi = (half_t*)take((size_t)3 * Dm * K1 * 2);
    half_t* Wohi = (half_t*)take((size_t)Dm * K1 * 2);
    half_t* W1lo = (half_t*)take((size_t)HD * K1 * 2);
    half_t* W2lo = (half_t*)take((size_t)Dm * K2 * 2);
    half_t* Wqlo = (half_t*)take((size_t)3 * Dm * K1 * 2);
    half_t* Wolo = (half_t*)take((size_t)Dm * K1 * 2);
    char*   A    = take((size_t)152 * MB);
    (void)ws_size; (void)in_sizes; (void)n_in; (void)out_size;

    // arena phase map (MB):
    // A: E1 @0..72 | H1 fp32 @72..104
    // B: E2c @0..72 | H1 @72..104 | P2 @104..136 (4x8) | H2 @136..152
    // C: E3 @0..72 | Q @72..80 K @80..88 V @88..96 | H2 @136..152
    // D: Vt @96..104 (V dead) | Schk fp16 @0..64 all 32bh (E3 dead) | in-place softmax | AO fp32 @104..120
    // E: E4 @0..72 (Schk dead) | P3 @120..152 (2x16) | Ofp = P3 slice0 @120..136
    half_t* E1   = (half_t*)(A);
    float*  H1   = (float*)(A + 72 * MB);
    half_t* E2   = (half_t*)(A);
    float*  P2   = (float*)(A + 104 * MB);
    float*  H2   = (float*)(A + 136 * MB);
    half_t* E3   = (half_t*)(A);
    half_t* Qb   = (half_t*)(A + 72 * MB);
    half_t* Kb   = (half_t*)(A + 80 * MB);
    half_t* Vb   = (half_t*)(A + 88 * MB);
    half_t* Vt   = (half_t*)(A + 96 * MB);
    half_t* Schk = (half_t*)(A);
    float*  AO   = (float*)(A + 104 * MB);
    half_t* E4   = (half_t*)(A);
    float*  P3   = (float*)(A + 120 * MB);
    float*  Ofp  = P3;

    pack_kernel<Dm><<<(HD * Dm) / 256, 256, 0, stream>>>(k1_base, k1_spline, W1hi, W1lo, HD);
    pack_kernel<HD><<<(Dm * HD) / 256, 256, 0, stream>>>(k2_base, k2_spline, W2hi, W2lo, Dm);
    pack_kernel<Dm><<<(Dm * Dm) / 256, 256, 0, stream>>>(q_base, q_spline, Wqhi, Wqlo, Dm);
    pack_kernel<Dm><<<(Dm * Dm) / 256, 256, 0, stream>>>(k_base, k_spline, Wqhi + (size_t)Dm * K1, Wqlo + (size_t)Dm * K1, Dm);
    pack_kernel<Dm><<<(Dm * Dm) / 256, 256, 0, stream>>>(v_base, v_spline, Wqhi + (size_t)2 * Dm * K1, Wqlo + (size_t)2 * Dm * K1, Dm);
    pack_kernel<Dm><<<(Dm * Dm) / 256, 256, 0, stream>>>(o_base, o_spline, Wohi, Wolo, Dm);

    // KAN1: direct ReLU epilogue, grid 64x8 = 512 (2/CU exact)
    expand_kernel<Dm><<<(NR * Dm) / 256, 256, 0, stream>>>(x, E1, NR);
    gemm_s<EPI_RELU, 1><<<dim3(NR / 128, HD / 128, 1), 128, 0, stream>>>(
        (const ushort_t*)E1, (const ushort_t*)W1hi, (const ushort_t*)W1lo,
        H1, nullptr, nullptr, nullptr, nullptr, NR, HD, K1);

    // KAN2 (2 M-chunks, KSPLIT=4): grid 32x4x4 = 512 (2/CU exact)
    for (int c = 0; c < 2; ++c) {
        expand_kernel<HD><<<(4096 * HD) / 256, 256, 0, stream>>>(H1 + (size_t)c * 4096 * HD, E2, 4096);
        gemm_s<EPI_PART, 4><<<dim3(4096 / 128, Dm / 128, 4), 128, 0, stream>>>(
            (const ushort_t*)E2, (const ushort_t*)W2hi, (const ushort_t*)W2lo,
            nullptr, P2, nullptr, nullptr, nullptr, 4096, Dm, K2);
        reduce_kernel<4, false><<<(4096 * Dm) / 1024, 256, 0, stream>>>(P2, H2 + (size_t)c * 4096 * Dm, (long)4096 * Dm);
    }

    // QKV: direct scatter, grid 64x12 = 768 (3/CU exact, single round); Q/K stripes hi-only
    expand_kernel<Dm><<<(NR * Dm) / 256, 256, 0, stream>>>(H2, E3, NR);
    gemm_s<EPI_QKV, 1><<<dim3(NR / 128, (3 * Dm) / 128, 1), 128, 0, stream>>>(
        (const ushort_t*)E3, (const ushort_t*)Wqhi, (const ushort_t*)Wqlo,
        nullptr, nullptr, Qb, Kb, Vb, NR, 3 * Dm, K1);

    // attention: Vt; single 32-bh S dispatch (fp16); in-place softmax; single 256-block PV
    transpose_v<<<dim3(16, 2, 32), 256, 0, stream>>>((const ushort_t*)Vb, (ushort_t*)Vt);
    gemm_t<EPI_SH><<<dim3(8, 8, 32), 256, 0, stream>>>(
        (const ushort_t*)Qb, (const ushort_t*)Kb,
        nullptr, Schk, 1024, 1024, 128, SQ, SQ, SS, 0.08838834764831845f);
    softmax_kernel<<<(32 * 1024) / 4, 256, 0, stream>>>(Schk, Schk);
    gemm_t<EPI_PV><<<dim3(8, 1, 32), 256, 0, stream>>>(
        (const ushort_t*)Schk, (const ushort_t*)Vt, AO, nullptr,
        1024, 128, 1024, SS, SQ, 0, 1.f);

    // O-proj: KSPLIT=2 (hi | lo), grid 64x4x2 = 512 (2/CU exact)
    expand_kernel<Dm><<<(NR * Dm) / 256, 256, 0, stream>>>(AO, E4, NR);
    gemm_s<EPI_PART, 2><<<dim3(NR / 128, Dm / 128, 2), 128, 0, stream>>>(
        (const ushort_t*)E4, (const ushort_t*)Wohi, (const ushort_t*)Wolo,
        nullptr, P3, nullptr, nullptr, nullptr, NR, Dm, K1);
    reduce_kernel<2, false><<<(NR * Dm) / 1024, 256, 0, stream>>>(P3, Ofp, (long)NR * Dm);

    // residual + LayerNorm
    ln_kernel<<<NR / 4, 256, 0, stream>>>(Ofp, x, ln_w, ln_b, out);
}

// Round 13
// 738.588 us; speedup vs baseline: 1.2400x; 1.2400x over previous
//
#include <hip/hip_runtime.h>
#include <cstdint>

typedef unsigned short ushort_t;
typedef _Float16 half_t;
typedef __attribute__((ext_vector_type(8))) short short8;
typedef __attribute__((ext_vector_type(8))) half_t half8;
typedef __attribute__((ext_vector_type(4))) half_t half4;
typedef __attribute__((ext_vector_type(4))) float f32x4;

// ---------------- helpers ----------------
__device__ __forceinline__ void gld_lds16(const ushort_t* g, ushort_t* l) {
    __builtin_amdgcn_global_load_lds((const __attribute__((address_space(1))) void*)g,
                                     (__attribute__((address_space(3))) void*)l,
                                     16, 0, 0);
}

// ---------------- expand: X fp32 [N][IN] -> E fp16 [N][9][IN] ----------------
template<int IN>
__global__ void expand_kernel(const float* __restrict__ X, half_t* __restrict__ E, int nrows) {
    int idx = blockIdx.x * 256 + threadIdx.x;
    if (idx >= nrows * IN) return;
    int n = idx / IN, i = idx % IN;
    float x = X[idx];
    float si = x / (1.0f + __expf(-x));
    float u = (x + 2.2f) * 2.5f;
    int ji = (int)floorf(u);
    float f = u - (float)ji;
    if (!(ji >= 0 && ji <= 10)) ji = -100;      // outside knot range -> all bases 0
    float f2 = f * f, f3 = f2 * f;
    float w_i   = f3 * (1.0f / 6.0f);
    float w_im1 = (1.0f + 3.0f * f + 3.0f * f2 - 3.0f * f3) * (1.0f/6.0f);
    float w_im2 = (4.0f - 6.0f * f2 + 3.0f * f3) * (1.0f/6.0f);
    float omf = 1.0f - f;
    float w_im3 = omf * omf * omf * (1.0f / 6.0f);
    half_t* Er = E + (long)n * 9 * IN + i;
    Er[0] = (half_t)si;
    #pragma unroll
    for (int c = 0; c < 8; ++c) {
        float v = 0.0f;
        v = (c == ji    ) ? w_i   : v;
        v = (c == ji - 1) ? w_im1 : v;
        v = (c == ji - 2) ? w_im2 : v;
        v = (c == ji - 3) ? w_im3 : v;
        Er[(long)(c + 1) * IN] = (half_t)v;
    }
}

// ---------------- pack weights hi/lo ----------------
template<int IN>
__global__ void pack_kernel(const float* __restrict__ base, const float* __restrict__ spline,
                            half_t* __restrict__ Whi, half_t* __restrict__ Wlo, int nout) {
    int idx = blockIdx.x * 256 + threadIdx.x;
    if (idx >= nout * IN) return;
    int o = idx / IN, i = idx % IN;
    long r0 = (long)o * 9 * IN + i;
    float w[9];
    w[0] = base[idx];
    const f32x4* sp = (const f32x4*)(spline + (long)idx * 8);
    f32x4 s0 = sp[0], s1 = sp[1];
    w[1] = s0[0]; w[2] = s0[1]; w[3] = s0[2]; w[4] = s0[3];
    w[5] = s1[0]; w[6] = s1[1]; w[7] = s1[2]; w[8] = s1[3];
    #pragma unroll
    for (int c = 0; c < 9; ++c) {
        half_t hi = (half_t)w[c];
        half_t lo = (half_t)(w[c] - (float)hi);
        Whi[r0 + (long)c * IN] = hi;
        Wlo[r0 + (long)c * IN] = lo;
    }
}

enum { EPI_PART = 0, EPI_QKV = 1, EPI_SH = 2, EPI_PV = 3, EPI_RELU = 4 };

// ---------------- weight GEMM: r6-proven 2-barrier structure (811 TF / 35.5% util) ----------------
// 128x128 tile, 4 waves (2x2), BK=64, 32 KB LDS -> 5 blocks/CU co-resident (m114 wave overlap).
// + r7-verified swizzle chunk^(row&7) on BOTH global source and ds_read (conflict-free, rule #21).
// Virtual tiles: NPASS==2 -> hi sweep then lo sweep (2*NT); NPASS==1 -> hi only.
// KSPLIT>1 slices the virtual range across blockIdx.z -> fp32 partials P[z].
template<int EPI, int NPASS, int KSPLIT>
__global__ __launch_bounds__(256, 4)
void gemm_w(const ushort_t* __restrict__ A, const ushort_t* __restrict__ Bhi,
            const ushort_t* __restrict__ Blo, float* __restrict__ Cf, float* __restrict__ P,
            half_t* __restrict__ Qp, half_t* __restrict__ Kp, half_t* __restrict__ Vp,
            int M, int N, int K) {
    __shared__ __attribute__((aligned(16))) ushort_t As[128 * 64];
    __shared__ __attribute__((aligned(16))) ushort_t Bs[128 * 64];
    const int tid = threadIdx.x;
    const int lane = tid & 63;
    const int wave = tid >> 6;
    const int wm = wave >> 1, wn = wave & 1;
    const int bm = blockIdx.x * 128, bn = blockIdx.y * 128;
    const int l15 = lane & 15, l16 = lane >> 4;
    const int NT = K >> 6;
    const int TV = (NPASS == 2) ? 2 * NT : NT;
    int kc, t0;
    if constexpr (KSPLIT > 1) { kc = TV / KSPLIT; t0 = blockIdx.z * kc; }
    else { kc = TV; t0 = 0; }

    f32x4 acc[4][4];
    #pragma unroll
    for (int m = 0; m < 4; ++m)
        #pragma unroll
        for (int n = 0; n < 4; ++n) acc[m][n] = (f32x4){0.f, 0.f, 0.f, 0.f};

    for (int u = 0; u < kc; ++u) {
        int tt = t0 + u;
        int pass = (tt >= NT) ? 1 : 0;
        int kt = (tt - (pass ? NT : 0)) << 6;
        const ushort_t* Bb = pass ? Blo : Bhi;
        #pragma unroll
        for (int r = 0; r < 4; ++r) {
            int ch = r * 256 + tid;             // 1024 chunks of 8 halves per 128x64 tile
            int row = ch >> 3, c = ch & 7;
            gld_lds16(A + (long)(bm + row) * K + kt + ((c ^ (row & 7)) << 3), &As[ch * 8]);
        }
        #pragma unroll
        for (int r = 0; r < 4; ++r) {
            int ch = r * 256 + tid;
            int row = ch >> 3, c = ch & 7;
            gld_lds16(Bb + (long)(bn + row) * K + kt + ((c ^ (row & 7)) << 3), &Bs[ch * 8]);
        }
        __syncthreads();
        #pragma unroll
        for (int kk = 0; kk < 2; ++kk) {
            half8 af[4], bfr[4];
            #pragma unroll
            for (int m = 0; m < 4; ++m) {
                int row = wm * 64 + m * 16 + l15;
                af[m] = __builtin_bit_cast(half8, *(const short8*)&As[row * 64 + (((kk * 4 + l16) ^ (row & 7)) << 3)]);
            }
            #pragma unroll
            for (int n = 0; n < 4; ++n) {
                int row = wn * 64 + n * 16 + l15;
                bfr[n] = __builtin_bit_cast(half8, *(const short8*)&Bs[row * 64 + (((kk * 4 + l16) ^ (row & 7)) << 3)]);
            }
            #pragma unroll
            for (int m = 0; m < 4; ++m)
                #pragma unroll
                for (int n = 0; n < 4; ++n)
                    acc[m][n] = __builtin_amdgcn_mfma_f32_16x16x32_f16(af[m], bfr[n], acc[m][n], 0, 0, 0);
        }
        __syncthreads();
    }

    // epilogue: C/D layout col=lane&15, row=(lane>>4)*4+j (m89-verified)
    #pragma unroll
    for (int m = 0; m < 4; ++m) {
        #pragma unroll
        for (int n = 0; n < 4; ++n) {
            #pragma unroll
            for (int j = 0; j < 4; ++j) {
                int row = bm + wm * 64 + m * 16 + l16 * 4 + j;
                int col = bn + wn * 64 + n * 16 + l15;
                float v = acc[m][n][j];
                if constexpr (KSPLIT > 1) {
                    P[(size_t)blockIdx.z * M * N + (long)row * N + col] = v;
                } else if constexpr (EPI == EPI_RELU) {
                    Cf[(long)row * N + col] = fmaxf(v, 0.0f);
                } else if constexpr (EPI == EPI_QKV) {
                    int which = col >> 9, w5 = col & 511, h = w5 >> 7, d = w5 & 127;
                    int b = row >> 10, ss = row & 1023;
                    half_t* dst = (which == 0) ? Qp : ((which == 1) ? Kp : Vp);
                    dst[(((long)(b * 4 + h) * 1024 + ss) << 7) + d] = (half_t)v;
                }
            }
        }
    }
}

// ---------------- legacy 128x128 GEMM (attention: S-half and PV) ----------------
template<int EPI>
__global__ void gemm_t(const ushort_t* __restrict__ A, const ushort_t* __restrict__ B,
                       float* __restrict__ Cf, half_t* __restrict__ Sh,
                       int M, int N, int K, long sA, long sB, long sC, float scale) {
    __shared__ ushort_t As[128 * 64];
    __shared__ ushort_t Bs[128 * 64];
    const int tid = threadIdx.x;
    const int lane = tid & 63;
    const int wave = tid >> 6;
    const int wm = wave >> 1, wn = wave & 1;
    const int bm = blockIdx.x * 128, bn = blockIdx.y * 128;
    const int z = blockIdx.z;
    const int l15 = lane & 15, l16 = lane >> 4;
    const ushort_t* Ab = A + (long)z * sA;
    const ushort_t* Bb = B + (long)z * sB;

    f32x4 acc[4][4];
    #pragma unroll
    for (int m = 0; m < 4; ++m)
        #pragma unroll
        for (int n = 0; n < 4; ++n) acc[m][n] = (f32x4){0.f, 0.f, 0.f, 0.f};

    for (int kt = 0; kt < K; kt += 64) {
        #pragma unroll
        for (int r = 0; r < 4; ++r) {
            int chunk = r * 256 + tid;
            gld_lds16(Ab + (long)(bm + (chunk >> 3)) * K + kt + ((chunk & 7) << 3), &As[chunk * 8]);
        }
        #pragma unroll
        for (int r = 0; r < 4; ++r) {
            int chunk = r * 256 + tid;
            gld_lds16(Bb + (long)(bn + (chunk >> 3)) * K + kt + ((chunk & 7) << 3), &Bs[chunk * 8]);
        }
        __syncthreads();
        #pragma unroll
        for (int kk = 0; kk < 2; ++kk) {
            half8 af[4], bfr[4];
            #pragma unroll
            for (int m = 0; m < 4; ++m)
                af[m] = __builtin_bit_cast(half8, *(const short8*)&As[(wm * 64 + m * 16 + l15) * 64 + kk * 32 + l16 * 8]);
            #pragma unroll
            for (int n = 0; n < 4; ++n)
                bfr[n] = __builtin_bit_cast(half8, *(const short8*)&Bs[(wn * 64 + n * 16 + l15) * 64 + kk * 32 + l16 * 8]);
            #pragma unroll
            for (int m = 0; m < 4; ++m)
                #pragma unroll
                for (int n = 0; n < 4; ++n)
                    acc[m][n] = __builtin_amdgcn_mfma_f32_16x16x32_f16(af[m], bfr[n], acc[m][n], 0, 0, 0);
        }
        __syncthreads();
    }

    #pragma unroll
    for (int m = 0; m < 4; ++m) {
        #pragma unroll
        for (int n = 0; n < 4; ++n) {
            #pragma unroll
            for (int j = 0; j < 4; ++j) {
                int row = bm + wm * 64 + m * 16 + l16 * 4 + j;
                int col = bn + wn * 64 + n * 16 + l15;
                float v = acc[m][n][j];
                if constexpr (EPI == EPI_SH) {
                    Sh[(long)z * sC + (long)row * N + col] = (half_t)(v * scale);
                } else if constexpr (EPI == EPI_PV) {
                    int b = z >> 2, h = z & 3;
                    Cf[((long)(b * 1024 + row) * 512) + h * 128 + col] = v;
                }
            }
        }
    }
}

// ---------------- split-K reduction ----------------
template<int KS, bool RELU>
__global__ void reduce_kernel(const float* __restrict__ P, float* __restrict__ out, long MN) {
    long i = ((long)blockIdx.x * 256 + threadIdx.x) * 4;
    if (i >= MN) return;
    f32x4 s = *(const f32x4*)&P[i];
    #pragma unroll
    for (int zz = 1; zz < KS; ++zz) {
        f32x4 t = *(const f32x4*)&P[(size_t)zz * MN + i];
        s += t;
    }
    if constexpr (RELU) {
        s[0] = fmaxf(s[0], 0.f); s[1] = fmaxf(s[1], 0.f);
        s[2] = fmaxf(s[2], 0.f); s[3] = fmaxf(s[3], 0.f);
    }
    *(f32x4*)&out[i] = s;
}

// ---------------- V transpose ----------------
__global__ void transpose_v(const ushort_t* __restrict__ V, ushort_t* __restrict__ Vt) {
    __shared__ ushort_t t[64][72];
    int s0 = blockIdx.x * 64, d0 = blockIdx.y * 64, bh = blockIdx.z;
    const ushort_t* Vb = V + (long)bh * 1024 * 128;
    ushort_t* Vtb = Vt + (long)bh * 128 * 1024;
    int tid = threadIdx.x;
    int r = tid >> 2, g = tid & 3;
    #pragma unroll
    for (int j = 0; j < 16; ++j)
        t[r][g * 16 + j] = Vb[(long)(s0 + r) * 128 + d0 + g * 16 + j];
    __syncthreads();
    #pragma unroll
    for (int j = 0; j < 16; ++j)
        Vtb[(long)(d0 + r) * 1024 + s0 + g * 16 + j] = t[g * 16 + j][r];
}

// ---------------- softmax over rows of 1024, fp16, in-place safe (row-local) ----------------
__global__ void softmax_kernel(const half_t* __restrict__ S, half_t* __restrict__ P) {
    long row = (long)blockIdx.x * 4 + (threadIdx.x >> 6);
    int lane = threadIdx.x & 63;
    const half_t* Sr = S + row * 1024;
    float f[16];
    #pragma unroll
    for (int c = 0; c < 2; ++c) {
        half8 h = *(const half8*)&Sr[c * 512 + lane * 8];
        #pragma unroll
        for (int j = 0; j < 8; ++j) f[c * 8 + j] = (float)h[j];
    }
    float mx = -3.0e38f;
    #pragma unroll
    for (int j = 0; j < 16; ++j) mx = fmaxf(mx, f[j]);
    #pragma unroll
    for (int off = 32; off > 0; off >>= 1) mx = fmaxf(mx, __shfl_xor(mx, off));
    float sum = 0.0f;
    #pragma unroll
    for (int j = 0; j < 16; ++j) { f[j] = __expf(f[j] - mx); sum += f[j]; }
    #pragma unroll
    for (int off = 32; off > 0; off >>= 1) sum += __shfl_xor(sum, off);
    float inv = 1.0f / sum;
    half_t* Pr = P + row * 1024;
    #pragma unroll
    for (int c = 0; c < 2; ++c) {
        half8 o;
        #pragma unroll
        for (int j = 0; j < 8; ++j) o[j] = (half_t)(f[c * 8 + j] * inv);
        *(half8*)&Pr[c * 512 + lane * 8] = o;
    }
}

// ---------------- residual + LayerNorm ----------------
__global__ void ln_kernel(const float* __restrict__ O, const float* __restrict__ X,
                          const float* __restrict__ g, const float* __restrict__ b,
                          float* __restrict__ out) {
    long row = (long)blockIdx.x * 4 + (threadIdx.x >> 6);
    int lane = threadIdx.x & 63;
    long base = row * 512 + lane * 8;
    f32x4 o0 = *(const f32x4*)&O[base], o1 = *(const f32x4*)&O[base + 4];
    f32x4 x0 = *(const f32x4*)&X[base], x1 = *(const f32x4*)&X[base + 4];
    float y[8];
    #pragma unroll
    for (int j = 0; j < 4; ++j) { y[j] = o0[j] + x0[j]; y[j + 4] = o1[j] + x1[j]; }
    float s = 0.f;
    #pragma unroll
    for (int j = 0; j < 8; ++j) s += y[j];
    #pragma unroll
    for (int off = 32; off > 0; off >>= 1) s += __shfl_xor(s, off);
    float mu = s * (1.0f / 512.0f);
    float vs = 0.f;
    #pragma unroll
    for (int j = 0; j < 8; ++j) { float d = y[j] - mu; vs += d * d; }
    #pragma unroll
    for (int off = 32; off > 0; off >>= 1) vs += __shfl_xor(vs, off);
    float r = rsqrtf(vs * (1.0f / 512.0f) + 1e-5f);
    f32x4 w0 = *(const f32x4*)&g[lane * 8], w1 = *(const f32x4*)&g[lane * 8 + 4];
    f32x4 b0 = *(const f32x4*)&b[lane * 8], b1 = *(const f32x4*)&b[lane * 8 + 4];
    f32x4 r0, r1;
    #pragma unroll
    for (int j = 0; j < 4; ++j) {
        r0[j] = (y[j] - mu) * r * w0[j] + b0[j];
        r1[j] = (y[j + 4] - mu) * r * w1[j] + b1[j];
    }
    *(f32x4*)&out[base] = r0;
    *(f32x4*)&out[base + 4] = r1;
}

// ---------------- launch ----------------
extern "C" void kernel_launch(void* const* d_in, const int* in_sizes, int n_in,
                              void* d_out, int out_size, void* d_ws, size_t ws_size,
                              hipStream_t stream) {
    const float* x         = (const float*)d_in[0];
    const float* k1_base   = (const float*)d_in[1];
    const float* k1_spline = (const float*)d_in[2];
    const float* k2_base   = (const float*)d_in[3];
    const float* k2_spline = (const float*)d_in[4];
    const float* q_base    = (const float*)d_in[5];
    const float* q_spline  = (const float*)d_in[6];
    const float* k_base    = (const float*)d_in[7];
    const float* k_spline  = (const float*)d_in[8];
    const float* v_base    = (const float*)d_in[9];
    const float* v_spline  = (const float*)d_in[10];
    const float* o_base    = (const float*)d_in[11];
    const float* o_spline  = (const float*)d_in[12];
    const float* ln_w      = (const float*)d_in[13];
    const float* ln_b      = (const float*)d_in[14];
    float* out = (float*)d_out;

    constexpr int Dm = 512, HD = 1024, NR = 8192;
    constexpr int K1 = 9 * Dm;   // 4608
    constexpr int K2 = 9 * HD;   // 9216
    constexpr long SQ = (long)1024 * 128;
    constexpr long SS = (long)1024 * 1024;
    constexpr size_t MB = 1024 * 1024;

    char* p = (char*)d_ws;
    size_t off = 0;
    auto take = [&](size_t bytes) -> char* {
        char* r = p + off;
        off += (bytes + 255) & ~(size_t)255;
        return r;
    };
    half_t* W1hi = (half_t*)take((size_t)HD * K1 * 2);
    half_t* W2hi = (half_t*)take((size_t)Dm * K2 * 2);
    half_t* Wqhi = (half_t*)take((size_t)3 * Dm * K1 * 2);
    half_t* Wohi = (half_t*)take((size_t)Dm * K1 * 2);
    half_t* W1lo = (half_t*)take((size_t)HD * K1 * 2);
    half_t* W2lo = (half_t*)take((size_t)Dm * K2 * 2);
    half_t* Wqlo = (half_t*)take((size_t)3 * Dm * K1 * 2);
    half_t* Wolo = (half_t*)take((size_t)Dm * K1 * 2);
    char*   A    = take((size_t)152 * MB);
    (void)ws_size; (void)in_sizes; (void)n_in; (void)out_size;

    // arena phase map (MB):
    // A: E1 @0..72 | H1 fp32 @72..104 (direct ReLU epilogue)
    // B: E2c @0..72 | H1 @72..104 | P2 @104..136 (4x8) | H2 @136..152
    // C: E3 @0..72 | Q @72..80 K @80..88 V @88..96 | H2 @136..152
    // D: Vt @96..104 (V dead) | Schk fp16 @0..64 all 32bh (E3 dead) | in-place softmax | AO fp32 @104..120
    // E: E4 @0..72 (Schk dead) | P3 @120..152 (2x16) | Ofp = P3 slice0 @120..136
    half_t* E1   = (half_t*)(A);
    float*  H1   = (float*)(A + 72 * MB);
    half_t* E2   = (half_t*)(A);
    float*  P2   = (float*)(A + 104 * MB);
    float*  H2   = (float*)(A + 136 * MB);
    half_t* E3   = (half_t*)(A);
    half_t* Qb   = (half_t*)(A + 72 * MB);
    half_t* Kb   = (half_t*)(A + 80 * MB);
    half_t* Vb   = (half_t*)(A + 88 * MB);
    half_t* Vt   = (half_t*)(A + 96 * MB);
    half_t* Schk = (half_t*)(A);
    float*  AO   = (float*)(A + 104 * MB);
    half_t* E4   = (half_t*)(A);
    float*  P3   = (float*)(A + 120 * MB);
    float*  Ofp  = P3;

    pack_kernel<Dm><<<(HD * Dm) / 256, 256, 0, stream>>>(k1_base, k1_spline, W1hi, W1lo, HD);
    pack_kernel<HD><<<(Dm * HD) / 256, 256, 0, stream>>>(k2_base, k2_spline, W2hi, W2lo, Dm);
    pack_kernel<Dm><<<(Dm * Dm) / 256, 256, 0, stream>>>(q_base, q_spline, Wqhi, Wqlo, Dm);
    pack_kernel<Dm><<<(Dm * Dm) / 256, 256, 0, stream>>>(k_base, k_spline, Wqhi + (size_t)Dm * K1, Wqlo + (size_t)Dm * K1, Dm);
    pack_kernel<Dm><<<(Dm * Dm) / 256, 256, 0, stream>>>(v_base, v_spline, Wqhi + (size_t)2 * Dm * K1, Wqlo + (size_t)2 * Dm * K1, Dm);
    pack_kernel<Dm><<<(Dm * Dm) / 256, 256, 0, stream>>>(o_base, o_spline, Wohi, Wolo, Dm);

    // KAN1: hi+lo serial, direct ReLU epilogue, grid 64x8 = 512 (2/CU; 5 allowed by 32KB LDS)
    expand_kernel<Dm><<<(NR * Dm) / 256, 256, 0, stream>>>(x, E1, NR);
    gemm_w<EPI_RELU, 2, 1><<<dim3(NR / 128, HD / 128, 1), 256, 0, stream>>>(
        (const ushort_t*)E1, (const ushort_t*)W1hi, (const ushort_t*)W1lo,
        H1, nullptr, nullptr, nullptr, nullptr, NR, HD, K1);

    // KAN2 (2 M-chunks, hi+lo, KSPLIT=4): grid 32x4x4 = 512
    for (int c = 0; c < 2; ++c) {
        expand_kernel<HD><<<(4096 * HD) / 256, 256, 0, stream>>>(H1 + (size_t)c * 4096 * HD, E2, 4096);
        gemm_w<EPI_PART, 2, 4><<<dim3(4096 / 128, Dm / 128, 4), 256, 0, stream>>>(
            (const ushort_t*)E2, (const ushort_t*)W2hi, (const ushort_t*)W2lo,
            nullptr, P2, nullptr, nullptr, nullptr, 4096, Dm, K2);
        reduce_kernel<4, false><<<(4096 * Dm) / 1024, 256, 0, stream>>>(P2, H2 + (size_t)c * 4096 * Dm, (long)4096 * Dm);
    }

    // QKV: hi-only single pass (Q,K,V), direct scatter, grid 64x12 = 768 (3/CU)
    expand_kernel<Dm><<<(NR * Dm) / 256, 256, 0, stream>>>(H2, E3, NR);
    gemm_w<EPI_QKV, 1, 1><<<dim3(NR / 128, (3 * Dm) / 128, 1), 256, 0, stream>>>(
        (const ushort_t*)E3, (const ushort_t*)Wqhi, (const ushort_t*)Wqlo,
        nullptr, nullptr, Qb, Kb, Vb, NR, 3 * Dm, K1);

    // attention: Vt; single 32-bh S (fp16); in-place softmax; single 256-block PV
    transpose_v<<<dim3(16, 2, 32), 256, 0, stream>>>((const ushort_t*)Vb, (ushort_t*)Vt);
    gemm_t<EPI_SH><<<dim3(8, 8, 32), 256, 0, stream>>>(
        (const ushort_t*)Qb, (const ushort_t*)Kb,
        nullptr, Schk, 1024, 1024, 128, SQ, SQ, SS, 0.08838834764831845f);
    softmax_kernel<<<(32 * 1024) / 4, 256, 0, stream>>>(Schk, Schk);
    gemm_t<EPI_PV><<<dim3(8, 1, 32), 256, 0, stream>>>(
        (const ushort_t*)Schk, (const ushort_t*)Vt, AO, nullptr,
        1024, 128, 1024, SS, SQ, 0, 1.f);

    // O-proj: hi-only, KSPLIT=2, grid 64x4x2 = 512
    expand_kernel<Dm><<<(NR * Dm) / 256, 256, 0, stream>>>(AO, E4, NR);
    gemm_w<EPI_PART, 1, 2><<<dim3(NR / 128, Dm / 128, 2), 256, 0, stream>>>(
        (const ushort_t*)E4, (const ushort_t*)Wohi, (const ushort_t*)Wolo,
        nullptr, P3, nullptr, nullptr, nullptr, NR, Dm, K1);
    reduce_kernel<2, false><<<(NR * Dm) / 1024, 256, 0, stream>>>(P3, Ofp, (long)NR * Dm);

    // residual + LayerNorm
    ln_kernel<<<NR / 4, 256, 0, stream>>>(Ofp, x, ln_w, ln_b, out);
}

// Round 15
// 717.842 us; speedup vs baseline: 1.2758x; 1.0289x over previous
//
#include <hip/hip_runtime.h>
#include <cstdint>

typedef unsigned short ushort_t;
typedef _Float16 half_t;
typedef __attribute__((ext_vector_type(8))) short short8;
typedef __attribute__((ext_vector_type(8))) half_t half8;
typedef __attribute__((ext_vector_type(4))) half_t half4;
typedef __attribute__((ext_vector_type(4))) float f32x4;

// ---------------- helpers ----------------
__device__ __forceinline__ void gld_lds16(const ushort_t* g, ushort_t* l) {
    __builtin_amdgcn_global_load_lds((const __attribute__((address_space(1))) void*)g,
                                     (__attribute__((address_space(3))) void*)l,
                                     16, 0, 0);
}

// ---------------- expand: X fp32 [N][IN] -> E fp16 [N][9][IN] ----------------
template<int IN>
__global__ void expand_kernel(const float* __restrict__ X, half_t* __restrict__ E, int nrows) {
    int idx = blockIdx.x * 256 + threadIdx.x;
    if (idx >= nrows * IN) return;
    int n = idx / IN, i = idx % IN;
    float x = X[idx];
    float si = x / (1.0f + __expf(-x));
    float u = (x + 2.2f) * 2.5f;
    int ji = (int)floorf(u);
    float f = u - (float)ji;
    if (!(ji >= 0 && ji <= 10)) ji = -100;      // outside knot range -> all bases 0
    float f2 = f * f, f3 = f2 * f;
    float w_i   = f3 * (1.0f / 6.0f);
    float w_im1 = (1.0f + 3.0f * f + 3.0f * f2 - 3.0f * f3) * (1.0f/6.0f);
    float w_im2 = (4.0f - 6.0f * f2 + 3.0f * f3) * (1.0f/6.0f);
    float omf = 1.0f - f;
    float w_im3 = omf * omf * omf * (1.0f / 6.0f);
    half_t* Er = E + (long)n * 9 * IN + i;
    Er[0] = (half_t)si;
    #pragma unroll
    for (int c = 0; c < 8; ++c) {
        float v = 0.0f;
        v = (c == ji    ) ? w_i   : v;
        v = (c == ji - 1) ? w_im1 : v;
        v = (c == ji - 2) ? w_im2 : v;
        v = (c == ji - 3) ? w_im3 : v;
        Er[(long)(c + 1) * IN] = (half_t)v;
    }
}

// ---------------- pack weights hi/lo ----------------
template<int IN>
__global__ void pack_kernel(const float* __restrict__ base, const float* __restrict__ spline,
                            half_t* __restrict__ Whi, half_t* __restrict__ Wlo, int nout) {
    int idx = blockIdx.x * 256 + threadIdx.x;
    if (idx >= nout * IN) return;
    int o = idx / IN, i = idx % IN;
    long r0 = (long)o * 9 * IN + i;
    float w[9];
    w[0] = base[idx];
    const f32x4* sp = (const f32x4*)(spline + (long)idx * 8);
    f32x4 s0 = sp[0], s1 = sp[1];
    w[1] = s0[0]; w[2] = s0[1]; w[3] = s0[2]; w[4] = s0[3];
    w[5] = s1[0]; w[6] = s1[1]; w[7] = s1[2]; w[8] = s1[3];
    #pragma unroll
    for (int c = 0; c < 9; ++c) {
        half_t hi = (half_t)w[c];
        half_t lo = (half_t)(w[c] - (float)hi);
        Whi[r0 + (long)c * IN] = hi;
        Wlo[r0 + (long)c * IN] = lo;
    }
}

enum { EPI_PART = 0, EPI_QKV = 1, EPI_SH = 2, EPI_PV = 3, EPI_RELU = 4 };

// ---------------- weight GEMM: r6-proven 2-barrier structure (875 TF measured r13) ----------------
// 128x128 tile, 4 waves (2x2), BK=64, 32 KB LDS -> 5 blocks/CU co-resident (m114 wave overlap).
// + r7-verified swizzle chunk^(row&7) on BOTH global source and ds_read (conflict-free, rule #21).
// Virtual tiles: NPASS==2 -> hi sweep then lo sweep (2*NT); NPASS==1 -> hi only.
// KSPLIT>1 slices the virtual range across blockIdx.z -> fp32 partials P[z].
template<int EPI, int NPASS, int KSPLIT>
__global__ __launch_bounds__(256, 4)
void gemm_w(const ushort_t* __restrict__ A, const ushort_t* __restrict__ Bhi,
            const ushort_t* __restrict__ Blo, float* __restrict__ Cf, float* __restrict__ P,
            half_t* __restrict__ Qp, half_t* __restrict__ Kp, half_t* __restrict__ Vp,
            int M, int N, int K) {
    __shared__ __attribute__((aligned(16))) ushort_t As[128 * 64];
    __shared__ __attribute__((aligned(16))) ushort_t Bs[128 * 64];
    const int tid = threadIdx.x;
    const int lane = tid & 63;
    const int wave = tid >> 6;
    const int wm = wave >> 1, wn = wave & 1;
    const int bm = blockIdx.x * 128, bn = blockIdx.y * 128;
    const int l15 = lane & 15, l16 = lane >> 4;
    const int NT = K >> 6;
    const int TV = (NPASS == 2) ? 2 * NT : NT;
    int kc, t0;
    if constexpr (KSPLIT > 1) { kc = TV / KSPLIT; t0 = blockIdx.z * kc; }
    else { kc = TV; t0 = 0; }

    f32x4 acc[4][4];
    #pragma unroll
    for (int m = 0; m < 4; ++m)
        #pragma unroll
        for (int n = 0; n < 4; ++n) acc[m][n] = (f32x4){0.f, 0.f, 0.f, 0.f};

    for (int u = 0; u < kc; ++u) {
        int tt = t0 + u;
        int pass = (tt >= NT) ? 1 : 0;
        int kt = (tt - (pass ? NT : 0)) << 6;
        const ushort_t* Bb = pass ? Blo : Bhi;
        #pragma unroll
        for (int r = 0; r < 4; ++r) {
            int ch = r * 256 + tid;             // 1024 chunks of 8 halves per 128x64 tile
            int row = ch >> 3, c = ch & 7;
            gld_lds16(A + (long)(bm + row) * K + kt + ((c ^ (row & 7)) << 3), &As[ch * 8]);
        }
        #pragma unroll
        for (int r = 0; r < 4; ++r) {
            int ch = r * 256 + tid;
            int row = ch >> 3, c = ch & 7;
            gld_lds16(Bb + (long)(bn + row) * K + kt + ((c ^ (row & 7)) << 3), &Bs[ch * 8]);
        }
        __syncthreads();
        #pragma unroll
        for (int kk = 0; kk < 2; ++kk) {
            half8 af[4], bfr[4];
            #pragma unroll
            for (int m = 0; m < 4; ++m) {
                int row = wm * 64 + m * 16 + l15;
                af[m] = __builtin_bit_cast(half8, *(const short8*)&As[row * 64 + (((kk * 4 + l16) ^ (row & 7)) << 3)]);
            }
            #pragma unroll
            for (int n = 0; n < 4; ++n) {
                int row = wn * 64 + n * 16 + l15;
                bfr[n] = __builtin_bit_cast(half8, *(const short8*)&Bs[row * 64 + (((kk * 4 + l16) ^ (row & 7)) << 3)]);
            }
            #pragma unroll
            for (int m = 0; m < 4; ++m)
                #pragma unroll
                for (int n = 0; n < 4; ++n)
                    acc[m][n] = __builtin_amdgcn_mfma_f32_16x16x32_f16(af[m], bfr[n], acc[m][n], 0, 0, 0);
        }
        __syncthreads();
    }

    // epilogue: C/D layout col=lane&15, row=(lane>>4)*4+j (m89-verified)
    #pragma unroll
    for (int m = 0; m < 4; ++m) {
        #pragma unroll
        for (int n = 0; n < 4; ++n) {
            #pragma unroll
            for (int j = 0; j < 4; ++j) {
                int row = bm + wm * 64 + m * 16 + l16 * 4 + j;
                int col = bn + wn * 64 + n * 16 + l15;
                float v = acc[m][n][j];
                if constexpr (KSPLIT > 1) {
                    P[(size_t)blockIdx.z * M * N + (long)row * N + col] = v;
                } else if constexpr (EPI == EPI_RELU) {
                    Cf[(long)row * N + col] = fmaxf(v, 0.0f);
                } else if constexpr (EPI == EPI_QKV) {
                    int which = col >> 9, w5 = col & 511, h = w5 >> 7, d = w5 & 127;
                    int b = row >> 10, ss = row & 1023;
                    half_t* dst = (which == 0) ? Qp : ((which == 1) ? Kp : Vp);
                    dst[(((long)(b * 4 + h) * 1024 + ss) << 7) + d] = (half_t)v;
                }
            }
        }
    }
}

// ---------------- legacy 128x128 GEMM (attention: S-half and PV) ----------------
template<int EPI>
__global__ void gemm_t(const ushort_t* __restrict__ A, const ushort_t* __restrict__ B,
                       float* __restrict__ Cf, half_t* __restrict__ Sh,
                       int M, int N, int K, long sA, long sB, long sC, float scale) {
    __shared__ ushort_t As[128 * 64];
    __shared__ ushort_t Bs[128 * 64];
    const int tid = threadIdx.x;
    const int lane = tid & 63;
    const int wave = tid >> 6;
    const int wm = wave >> 1, wn = wave & 1;
    const int bm = blockIdx.x * 128, bn = blockIdx.y * 128;
    const int z = blockIdx.z;
    const int l15 = lane & 15, l16 = lane >> 4;
    const ushort_t* Ab = A + (long)z * sA;
    const ushort_t* Bb = B + (long)z * sB;

    f32x4 acc[4][4];
    #pragma unroll
    for (int m = 0; m < 4; ++m)
        #pragma unroll
        for (int n = 0; n < 4; ++n) acc[m][n] = (f32x4){0.f, 0.f, 0.f, 0.f};

    for (int kt = 0; kt < K; kt += 64) {
        #pragma unroll
        for (int r = 0; r < 4; ++r) {
            int chunk = r * 256 + tid;
            gld_lds16(Ab + (long)(bm + (chunk >> 3)) * K + kt + ((chunk & 7) << 3), &As[chunk * 8]);
        }
        #pragma unroll
        for (int r = 0; r < 4; ++r) {
            int chunk = r * 256 + tid;
            gld_lds16(Bb + (long)(bn + (chunk >> 3)) * K + kt + ((chunk & 7) << 3), &Bs[chunk * 8]);
        }
        __syncthreads();
        #pragma unroll
        for (int kk = 0; kk < 2; ++kk) {
            half8 af[4], bfr[4];
            #pragma unroll
            for (int m = 0; m < 4; ++m)
                af[m] = __builtin_bit_cast(half8, *(const short8*)&As[(wm * 64 + m * 16 + l15) * 64 + kk * 32 + l16 * 8]);
            #pragma unroll
            for (int n = 0; n < 4; ++n)
                bfr[n] = __builtin_bit_cast(half8, *(const short8*)&Bs[(wn * 64 + n * 16 + l15) * 64 + kk * 32 + l16 * 8]);
            #pragma unroll
            for (int m = 0; m < 4; ++m)
                #pragma unroll
                for (int n = 0; n < 4; ++n)
                    acc[m][n] = __builtin_amdgcn_mfma_f32_16x16x32_f16(af[m], bfr[n], acc[m][n], 0, 0, 0);
        }
        __syncthreads();
    }

    #pragma unroll
    for (int m = 0; m < 4; ++m) {
        #pragma unroll
        for (int n = 0; n < 4; ++n) {
            #pragma unroll
            for (int j = 0; j < 4; ++j) {
                int row = bm + wm * 64 + m * 16 + l16 * 4 + j;
                int col = bn + wn * 64 + n * 16 + l15;
                float v = acc[m][n][j];
                if constexpr (EPI == EPI_SH) {
                    Sh[(long)z * sC + (long)row * N + col] = (half_t)(v * scale);
                } else if constexpr (EPI == EPI_PV) {
                    int b = z >> 2, h = z & 3;
                    Cf[((long)(b * 1024 + row) * 512) + h * 128 + col] = v;
                }
            }
        }
    }
}

// ---------------- split-K reduction ----------------
template<int KS, bool RELU>
__global__ void reduce_kernel(const float* __restrict__ P, float* __restrict__ out, long MN) {
    long i = ((long)blockIdx.x * 256 + threadIdx.x) * 4;
    if (i >= MN) return;
    f32x4 s = *(const f32x4*)&P[i];
    #pragma unroll
    for (int zz = 1; zz < KS; ++zz) {
        f32x4 t = *(const f32x4*)&P[(size_t)zz * MN + i];
        s += t;
    }
    if constexpr (RELU) {
        s[0] = fmaxf(s[0], 0.f); s[1] = fmaxf(s[1], 0.f);
        s[2] = fmaxf(s[2], 0.f); s[3] = fmaxf(s[3], 0.f);
    }
    *(f32x4*)&out[i] = s;
}

// ---------------- V transpose ----------------
__global__ void transpose_v(const ushort_t* __restrict__ V, ushort_t* __restrict__ Vt) {
    __shared__ ushort_t t[64][72];
    int s0 = blockIdx.x * 64, d0 = blockIdx.y * 64, bh = blockIdx.z;
    const ushort_t* Vb = V + (long)bh * 1024 * 128;
    ushort_t* Vtb = Vt + (long)bh * 128 * 1024;
    int tid = threadIdx.x;
    int r = tid >> 2, g = tid & 3;
    #pragma unroll
    for (int j = 0; j < 16; ++j)
        t[r][g * 16 + j] = Vb[(long)(s0 + r) * 128 + d0 + g * 16 + j];
    __syncthreads();
    #pragma unroll
    for (int j = 0; j < 16; ++j)
        Vtb[(long)(d0 + r) * 1024 + s0 + g * 16 + j] = t[g * 16 + j][r];
}

// ---------------- softmax over rows of 1024, fp16, in-place safe (row-local) ----------------
__global__ void softmax_kernel(const half_t* __restrict__ S, half_t* __restrict__ P) {
    long row = (long)blockIdx.x * 4 + (threadIdx.x >> 6);
    int lane = threadIdx.x & 63;
    const half_t* Sr = S + row * 1024;
    float f[16];
    #pragma unroll
    for (int c = 0; c < 2; ++c) {
        half8 h = *(const half8*)&Sr[c * 512 + lane * 8];
        #pragma unroll
        for (int j = 0; j < 8; ++j) f[c * 8 + j] = (float)h[j];
    }
    float mx = -3.0e38f;
    #pragma unroll
    for (int j = 0; j < 16; ++j) mx = fmaxf(mx, f[j]);
    #pragma unroll
    for (int off = 32; off > 0; off >>= 1) mx = fmaxf(mx, __shfl_xor(mx, off));
    float sum = 0.0f;
    #pragma unroll
    for (int j = 0; j < 16; ++j) { f[j] = __expf(f[j] - mx); sum += f[j]; }
    #pragma unroll
    for (int off = 32; off > 0; off >>= 1) sum += __shfl_xor(sum, off);
    float inv = 1.0f / sum;
    half_t* Pr = P + row * 1024;
    #pragma unroll
    for (int c = 0; c < 2; ++c) {
        half8 o;
        #pragma unroll
        for (int j = 0; j < 8; ++j) o[j] = (half_t)(f[c * 8 + j] * inv);
        *(half8*)&Pr[c * 512 + lane * 8] = o;
    }
}

// ---------------- fused split-K2 reduce + residual + LayerNorm (rows of 512) ----------------
// y = P[0][row] + P[1][row] + X[row]; out = LN(y)*g + b. Same fp32 add order as the
// previous reduce<2> + ln pair (slice0+slice1, then +x).
__global__ void reduce2_ln_kernel(const float* __restrict__ P, long MN,
                                  const float* __restrict__ X,
                                  const float* __restrict__ g, const float* __restrict__ b,
                                  float* __restrict__ out) {
    long row = (long)blockIdx.x * 4 + (threadIdx.x >> 6);
    int lane = threadIdx.x & 63;
    long base = row * 512 + lane * 8;
    f32x4 p0 = *(const f32x4*)&P[base],      p1 = *(const f32x4*)&P[base + 4];
    f32x4 q0 = *(const f32x4*)&P[MN + base], q1 = *(const f32x4*)&P[MN + base + 4];
    f32x4 x0 = *(const f32x4*)&X[base],      x1 = *(const f32x4*)&X[base + 4];
    float y[8];
    #pragma unroll
    for (int j = 0; j < 4; ++j) {
        y[j]     = (p0[j] + q0[j]) + x0[j];
        y[j + 4] = (p1[j] + q1[j]) + x1[j];
    }
    float s = 0.f;
    #pragma unroll
    for (int j = 0; j < 8; ++j) s += y[j];
    #pragma unroll
    for (int off = 32; off > 0; off >>= 1) s += __shfl_xor(s, off);
    float mu = s * (1.0f / 512.0f);
    float vs = 0.f;
    #pragma unroll
    for (int j = 0; j < 8; ++j) { float d = y[j] - mu; vs += d * d; }
    #pragma unroll
    for (int off = 32; off > 0; off >>= 1) vs += __shfl_xor(vs, off);
    float r = rsqrtf(vs * (1.0f / 512.0f) + 1e-5f);
    f32x4 w0 = *(const f32x4*)&g[lane * 8], w1 = *(const f32x4*)&g[lane * 8 + 4];
    f32x4 b0 = *(const f32x4*)&b[lane * 8], b1 = *(const f32x4*)&b[lane * 8 + 4];
    f32x4 r0, r1;
    #pragma unroll
    for (int j = 0; j < 4; ++j) {
        r0[j] = (y[j] - mu) * r * w0[j] + b0[j];
        r1[j] = (y[j + 4] - mu) * r * w1[j] + b1[j];
    }
    *(f32x4*)&out[base] = r0;
    *(f32x4*)&out[base + 4] = r1;
}

// ---------------- launch ----------------
extern "C" void kernel_launch(void* const* d_in, const int* in_sizes, int n_in,
                              void* d_out, int out_size, void* d_ws, size_t ws_size,
                              hipStream_t stream) {
    const float* x         = (const float*)d_in[0];
    const float* k1_base   = (const float*)d_in[1];
    const float* k1_spline = (const float*)d_in[2];
    const float* k2_base   = (const float*)d_in[3];
    const float* k2_spline = (const float*)d_in[4];
    const float* q_base    = (const float*)d_in[5];
    const float* q_spline  = (const float*)d_in[6];
    const float* k_base    = (const float*)d_in[7];
    const float* k_spline  = (const float*)d_in[8];
    const float* v_base    = (const float*)d_in[9];
    const float* v_spline  = (const float*)d_in[10];
    const float* o_base    = (const float*)d_in[11];
    const float* o_spline  = (const float*)d_in[12];
    const float* ln_w      = (const float*)d_in[13];
    const float* ln_b      = (const float*)d_in[14];
    float* out = (float*)d_out;

    constexpr int Dm = 512, HD = 1024, NR = 8192;
    constexpr int K1 = 9 * Dm;   // 4608
    constexpr int K2 = 9 * HD;   // 9216
    constexpr long SQ = (long)1024 * 128;
    constexpr long SS = (long)1024 * 1024;
    constexpr size_t MB = 1024 * 1024;

    char* p = (char*)d_ws;
    size_t off = 0;
    auto take = [&](size_t bytes) -> char* {
        char* r = p + off;
        off += (bytes + 255) & ~(size_t)255;
        return r;
    };
    half_t* W1hi = (half_t*)take((size_t)HD * K1 * 2);
    half_t* W2hi = (half_t*)take((size_t)Dm * K2 * 2);
    half_t* Wqhi = (half_t*)take((size_t)3 * Dm * K1 * 2);
    half_t* Wohi = (half_t*)take((size_t)Dm * K1 * 2);
    half_t* W1lo = (half_t*)take((size_t)HD * K1 * 2);
    half_t* W2lo = (half_t*)take((size_t)Dm * K2 * 2);
    half_t* Wqlo = (half_t*)take((size_t)3 * Dm * K1 * 2);
    half_t* Wolo = (half_t*)take((size_t)Dm * K1 * 2);
    char*   A    = take((size_t)152 * MB);
    (void)ws_size; (void)in_sizes; (void)n_in; (void)out_size;

    // arena phase map (MB):
    // A: E1 @0..72 | H1 fp32 @72..104 (direct ReLU epilogue)
    // B: E2c @0..72 | H1 @72..104 | P2 @104..136 (4x8) | H2 @136..152
    // C: E3 @0..72 | Q @72..80 K @80..88 V @88..96 | H2 @136..152
    // D: Vt @96..104 (V dead) | Schk fp16 @0..64 all 32bh (E3 dead) | in-place softmax | AO fp32 @104..120
    // E: E4 @0..72 (Schk dead) | P3 @120..152 (2x16) | fused reduce2+LN reads P3 directly
    half_t* E1   = (half_t*)(A);
    float*  H1   = (float*)(A + 72 * MB);
    half_t* E2   = (half_t*)(A);
    float*  P2   = (float*)(A + 104 * MB);
    float*  H2   = (float*)(A + 136 * MB);
    half_t* E3   = (half_t*)(A);
    half_t* Qb   = (half_t*)(A + 72 * MB);
    half_t* Kb   = (half_t*)(A + 80 * MB);
    half_t* Vb   = (half_t*)(A + 88 * MB);
    half_t* Vt   = (half_t*)(A + 96 * MB);
    half_t* Schk = (half_t*)(A);
    float*  AO   = (float*)(A + 104 * MB);
    half_t* E4   = (half_t*)(A);
    float*  P3   = (float*)(A + 120 * MB);

    pack_kernel<Dm><<<(HD * Dm) / 256, 256, 0, stream>>>(k1_base, k1_spline, W1hi, W1lo, HD);
    pack_kernel<HD><<<(Dm * HD) / 256, 256, 0, stream>>>(k2_base, k2_spline, W2hi, W2lo, Dm);
    pack_kernel<Dm><<<(Dm * Dm) / 256, 256, 0, stream>>>(q_base, q_spline, Wqhi, Wqlo, Dm);
    pack_kernel<Dm><<<(Dm * Dm) / 256, 256, 0, stream>>>(k_base, k_spline, Wqhi + (size_t)Dm * K1, Wqlo + (size_t)Dm * K1, Dm);
    pack_kernel<Dm><<<(Dm * Dm) / 256, 256, 0, stream>>>(v_base, v_spline, Wqhi + (size_t)2 * Dm * K1, Wqlo + (size_t)2 * Dm * K1, Dm);
    pack_kernel<Dm><<<(Dm * Dm) / 256, 256, 0, stream>>>(o_base, o_spline, Wohi, Wolo, Dm);

    // KAN1: hi+lo serial (r14 proved lo-pass is required here), direct ReLU epilogue, grid 64x8
    expand_kernel<Dm><<<(NR * Dm) / 256, 256, 0, stream>>>(x, E1, NR);
    gemm_w<EPI_RELU, 2, 1><<<dim3(NR / 128, HD / 128, 1), 256, 0, stream>>>(
        (const ushort_t*)E1, (const ushort_t*)W1hi, (const ushort_t*)W1lo,
        H1, nullptr, nullptr, nullptr, nullptr, NR, HD, K1);

    // KAN2 (2 M-chunks, hi+lo, KSPLIT=4): grid 32x4x4 = 512
    for (int c = 0; c < 2; ++c) {
        expand_kernel<HD><<<(4096 * HD) / 256, 256, 0, stream>>>(H1 + (size_t)c * 4096 * HD, E2, 4096);
        gemm_w<EPI_PART, 2, 4><<<dim3(4096 / 128, Dm / 128, 4), 256, 0, stream>>>(
            (const ushort_t*)E2, (const ushort_t*)W2hi, (const ushort_t*)W2lo,
            nullptr, P2, nullptr, nullptr, nullptr, 4096, Dm, K2);
        reduce_kernel<4, false><<<(4096 * Dm) / 1024, 256, 0, stream>>>(P2, H2 + (size_t)c * 4096 * Dm, (long)4096 * Dm);
    }

    // QKV: hi-only single pass (Q,K,V), direct scatter, grid 64x12 = 768 (3/CU)
    expand_kernel<Dm><<<(NR * Dm) / 256, 256, 0, stream>>>(H2, E3, NR);
    gemm_w<EPI_QKV, 1, 1><<<dim3(NR / 128, (3 * Dm) / 128, 1), 256, 0, stream>>>(
        (const ushort_t*)E3, (const ushort_t*)Wqhi, (const ushort_t*)Wqlo,
        nullptr, nullptr, Qb, Kb, Vb, NR, 3 * Dm, K1);

    // attention: Vt; single 32-bh S (fp16); in-place softmax; single 256-block PV
    transpose_v<<<dim3(16, 2, 32), 256, 0, stream>>>((const ushort_t*)Vb, (ushort_t*)Vt);
    gemm_t<EPI_SH><<<dim3(8, 8, 32), 256, 0, stream>>>(
        (const ushort_t*)Qb, (const ushort_t*)Kb,
        nullptr, Schk, 1024, 1024, 128, SQ, SQ, SS, 0.08838834764831845f);
    softmax_kernel<<<(32 * 1024) / 4, 256, 0, stream>>>(Schk, Schk);
    gemm_t<EPI_PV><<<dim3(8, 1, 32), 256, 0, stream>>>(
        (const ushort_t*)Schk, (const ushort_t*)Vt, AO, nullptr,
        1024, 128, 1024, SS, SQ, 0, 1.f);

    // O-proj: hi-only, KSPLIT=2, grid 64x4x2 = 512; fused reduce2 + residual + LN
    expand_kernel<Dm><<<(NR * Dm) / 256, 256, 0, stream>>>(AO, E4, NR);
    gemm_w<EPI_PART, 1, 2><<<dim3(NR / 128, Dm / 128, 2), 256, 0, stream>>>(
        (const ushort_t*)E4, (const ushort_t*)Wohi, (const ushort_t*)Wolo,
        nullptr, P3, nullptr, nullptr, nullptr, NR, Dm, K1);
    reduce2_ln_kernel<<<NR / 4, 256, 0, stream>>>(P3, (long)NR * Dm, x, ln_w, ln_b, out);
}

// Round 16
// 712.766 us; speedup vs baseline: 1.2849x; 1.0071x over previous
//
#include <hip/hip_runtime.h>
#include <cstdint>

typedef unsigned short ushort_t;
typedef _Float16 half_t;
typedef __attribute__((ext_vector_type(8))) short short8;
typedef __attribute__((ext_vector_type(8))) half_t half8;
typedef __attribute__((ext_vector_type(4))) float f32x4;

// ---------------- helpers ----------------
__device__ __forceinline__ void gld_lds16(const ushort_t* g, ushort_t* l) {
    __builtin_amdgcn_global_load_lds((const __attribute__((address_space(1))) void*)g,
                                     (__attribute__((address_space(3))) void*)l,
                                     16, 0, 0);
}

// ---------------- expand: X fp32 [N][IN] -> E fp16 [N][9][IN] ----------------
template<int IN>
__global__ void expand_kernel(const float* __restrict__ X, half_t* __restrict__ E, int nrows) {
    int idx = blockIdx.x * 256 + threadIdx.x;
    if (idx >= nrows * IN) return;
    int n = idx / IN, i = idx % IN;
    float x = X[idx];
    float si = x / (1.0f + __expf(-x));
    float u = (x + 2.2f) * 2.5f;
    int ji = (int)floorf(u);
    float f = u - (float)ji;
    if (!(ji >= 0 && ji <= 10)) ji = -100;      // outside knot range -> all bases 0
    float f2 = f * f, f3 = f2 * f;
    float w_i   = f3 * (1.0f / 6.0f);
    float w_im1 = (1.0f + 3.0f * f + 3.0f * f2 - 3.0f * f3) * (1.0f/6.0f);
    float w_im2 = (4.0f - 6.0f * f2 + 3.0f * f3) * (1.0f/6.0f);
    float omf = 1.0f - f;
    float w_im3 = omf * omf * omf * (1.0f / 6.0f);
    half_t* Er = E + (long)n * 9 * IN + i;
    Er[0] = (half_t)si;
    #pragma unroll
    for (int c = 0; c < 8; ++c) {
        float v = 0.0f;
        v = (c == ji    ) ? w_i   : v;
        v = (c == ji - 1) ? w_im1 : v;
        v = (c == ji - 2) ? w_im2 : v;
        v = (c == ji - 3) ? w_im3 : v;
        Er[(long)(c + 1) * IN] = (half_t)v;
    }
}

// ---------------- pack weights hi/lo ----------------
template<int IN>
__global__ void pack_kernel(const float* __restrict__ base, const float* __restrict__ spline,
                            half_t* __restrict__ Whi, half_t* __restrict__ Wlo, int nout) {
    int idx = blockIdx.x * 256 + threadIdx.x;
    if (idx >= nout * IN) return;
    int o = idx / IN, i = idx % IN;
    long r0 = (long)o * 9 * IN + i;
    float w[9];
    w[0] = base[idx];
    const f32x4* sp = (const f32x4*)(spline + (long)idx * 8);
    f32x4 s0 = sp[0], s1 = sp[1];
    w[1] = s0[0]; w[2] = s0[1]; w[3] = s0[2]; w[4] = s0[3];
    w[5] = s1[0]; w[6] = s1[1]; w[7] = s1[2]; w[8] = s1[3];
    #pragma unroll
    for (int c = 0; c < 9; ++c) {
        half_t hi = (half_t)w[c];
        half_t lo = (half_t)(w[c] - (float)hi);
        Whi[r0 + (long)c * IN] = hi;
        Wlo[r0 + (long)c * IN] = lo;
    }
}

enum { EPI_PART = 0, EPI_QKV = 1, EPI_RELU = 4 };

// ---------------- weight GEMM: r6-proven 2-barrier structure (875 TF measured r13) ----------------
// 128x128 tile, 4 waves (2x2), BK=64, 32 KB LDS -> 5 blocks/CU co-resident (m114 wave overlap).
// + r7-verified swizzle chunk^(row&7) on BOTH global source and ds_read (conflict-free, rule #21).
// Virtual tiles: NPASS==2 -> hi sweep then lo sweep (2*NT); NPASS==1 -> hi only.
// KSPLIT>1 slices the virtual range across blockIdx.z -> fp32 partials P[z].
template<int EPI, int NPASS, int KSPLIT>
__global__ __launch_bounds__(256, 4)
void gemm_w(const ushort_t* __restrict__ A, const ushort_t* __restrict__ Bhi,
            const ushort_t* __restrict__ Blo, float* __restrict__ Cf, float* __restrict__ P,
            half_t* __restrict__ Qp, half_t* __restrict__ Kp, half_t* __restrict__ Vp,
            int M, int N, int K) {
    __shared__ __attribute__((aligned(16))) ushort_t As[128 * 64];
    __shared__ __attribute__((aligned(16))) ushort_t Bs[128 * 64];
    const int tid = threadIdx.x;
    const int lane = tid & 63;
    const int wave = tid >> 6;
    const int wm = wave >> 1, wn = wave & 1;
    const int bm = blockIdx.x * 128, bn = blockIdx.y * 128;
    const int l15 = lane & 15, l16 = lane >> 4;
    const int NT = K >> 6;
    const int TV = (NPASS == 2) ? 2 * NT : NT;
    int kc, t0;
    if constexpr (KSPLIT > 1) { kc = TV / KSPLIT; t0 = blockIdx.z * kc; }
    else { kc = TV; t0 = 0; }

    f32x4 acc[4][4];
    #pragma unroll
    for (int m = 0; m < 4; ++m)
        #pragma unroll
        for (int n = 0; n < 4; ++n) acc[m][n] = (f32x4){0.f, 0.f, 0.f, 0.f};

    for (int u = 0; u < kc; ++u) {
        int tt = t0 + u;
        int pass = (tt >= NT) ? 1 : 0;
        int kt = (tt - (pass ? NT : 0)) << 6;
        const ushort_t* Bb = pass ? Blo : Bhi;
        #pragma unroll
        for (int r = 0; r < 4; ++r) {
            int ch = r * 256 + tid;             // 1024 chunks of 8 halves per 128x64 tile
            int row = ch >> 3, c = ch & 7;
            gld_lds16(A + (long)(bm + row) * K + kt + ((c ^ (row & 7)) << 3), &As[ch * 8]);
        }
        #pragma unroll
        for (int r = 0; r < 4; ++r) {
            int ch = r * 256 + tid;
            int row = ch >> 3, c = ch & 7;
            gld_lds16(Bb + (long)(bn + row) * K + kt + ((c ^ (row & 7)) << 3), &Bs[ch * 8]);
        }
        __syncthreads();
        #pragma unroll
        for (int kk = 0; kk < 2; ++kk) {
            half8 af[4], bfr[4];
            #pragma unroll
            for (int m = 0; m < 4; ++m) {
                int row = wm * 64 + m * 16 + l15;
                af[m] = __builtin_bit_cast(half8, *(const short8*)&As[row * 64 + (((kk * 4 + l16) ^ (row & 7)) << 3)]);
            }
            #pragma unroll
            for (int n = 0; n < 4; ++n) {
                int row = wn * 64 + n * 16 + l15;
                bfr[n] = __builtin_bit_cast(half8, *(const short8*)&Bs[row * 64 + (((kk * 4 + l16) ^ (row & 7)) << 3)]);
            }
            #pragma unroll
            for (int m = 0; m < 4; ++m)
                #pragma unroll
                for (int n = 0; n < 4; ++n)
                    acc[m][n] = __builtin_amdgcn_mfma_f32_16x16x32_f16(af[m], bfr[n], acc[m][n], 0, 0, 0);
        }
        __syncthreads();
    }

    // epilogue: C/D layout col=lane&15, row=(lane>>4)*4+j (m89-verified)
    #pragma unroll
    for (int m = 0; m < 4; ++m) {
        #pragma unroll
        for (int n = 0; n < 4; ++n) {
            #pragma unroll
            for (int j = 0; j < 4; ++j) {
                int row = bm + wm * 64 + m * 16 + l16 * 4 + j;
                int col = bn + wn * 64 + n * 16 + l15;
                float v = acc[m][n][j];
                if constexpr (KSPLIT > 1) {
                    P[(size_t)blockIdx.z * M * N + (long)row * N + col] = v;
                } else if constexpr (EPI == EPI_RELU) {
                    Cf[(long)row * N + col] = fmaxf(v, 0.0f);
                } else if constexpr (EPI == EPI_QKV) {
                    int which = col >> 9, w5 = col & 511, h = w5 >> 7, d = w5 & 127;
                    int b = row >> 10, ss = row & 1023;
                    half_t* dst = (which == 0) ? Qp : ((which == 1) ? Kp : Vp);
                    dst[(((long)(b * 4 + h) * 1024 + ss) << 7) + d] = (half_t)v;
                }
            }
        }
    }
}

// ---------------- fused flash attention: S=QK^T/sqrt(d), online softmax, O=PV ----------------
// grid (8 q-tiles, 32 bh), 256 threads = 4 waves row-split (each wave: 32 q-rows x 128 cols
// -> softmax rows are wave-local; reduce = shfl_xor over l15 only). Q register-resident.
// Swizzle for 256B-stride tiles: chunk c16 ^ (row&15), applied on gld source AND ds_read
// AND Ps writes (rule #21). 3 x __syncthreads per KV iteration (conservative full drain).
__global__ __launch_bounds__(256, 1)
void flash_attn(const ushort_t* __restrict__ Q, const ushort_t* __restrict__ Kb,
                const ushort_t* __restrict__ Vt, float* __restrict__ AO, float scale) {
    constexpr int TS = 128 * 128;
    __shared__ __attribute__((aligned(16))) ushort_t Qs[TS];
    __shared__ __attribute__((aligned(16))) ushort_t Ks[TS];
    __shared__ __attribute__((aligned(16))) ushort_t Vs[TS];
    __shared__ __attribute__((aligned(16))) half_t  Ps[TS];
    const int tid = threadIdx.x;
    const int lane = tid & 63;
    const int w = tid >> 6;                    // wave 0..3 -> q-rows [w*32, w*32+32)
    const int l15 = lane & 15, l16 = lane >> 4;
    const int bm = blockIdx.x * 128;
    const int bh = blockIdx.y;
    const ushort_t* Qg = Q + (long)bh * 1024 * 128;
    const ushort_t* Kg = Kb + (long)bh * 1024 * 128;
    const ushort_t* Vg = Vt + (long)bh * 128 * 1024;

    // stage Q tile once (128 rows x 16 chunks of 8 halves; 8 chunks/thread)
    #pragma unroll
    for (int r = 0; r < 8; ++r) {
        int ch = r * 256 + tid;
        int row = ch >> 4, c = ch & 15;
        gld_lds16(Qg + (long)(bm + row) * 128 + ((c ^ (row & 15)) << 3), &Qs[ch * 8]);
    }
    __syncthreads();
    half8 qf[2][4];
    #pragma unroll
    for (int mf = 0; mf < 2; ++mf)
        #pragma unroll
        for (int kk = 0; kk < 4; ++kk) {
            int row = w * 32 + mf * 16 + l15;
            qf[mf][kk] = __builtin_bit_cast(half8, *(const short8*)&Qs[row * 128 + (((kk * 4 + l16) ^ (row & 15)) << 3)]);
        }

    f32x4 o_acc[2][8];
    #pragma unroll
    for (int mf = 0; mf < 2; ++mf)
        #pragma unroll
        for (int nf = 0; nf < 8; ++nf) o_acc[mf][nf] = (f32x4){0.f, 0.f, 0.f, 0.f};
    float m_run[2][4], l_run[2][4];
    #pragma unroll
    for (int mf = 0; mf < 2; ++mf)
        #pragma unroll
        for (int j = 0; j < 4; ++j) { m_run[mf][j] = -3.0e38f; l_run[mf][j] = 0.f; }

    for (int t = 0; t < 8; ++t) {
        int kv0 = t * 128;
        // stage K tile [s'][d] and V^T tile [d][s']
        #pragma unroll
        for (int r = 0; r < 8; ++r) {
            int ch = r * 256 + tid;
            int row = ch >> 4, c = ch & 15;
            gld_lds16(Kg + (long)(kv0 + row) * 128 + ((c ^ (row & 15)) << 3), &Ks[ch * 8]);
        }
        #pragma unroll
        for (int r = 0; r < 8; ++r) {
            int ch = r * 256 + tid;
            int row = ch >> 4, c = ch & 15;    // row = d
            gld_lds16(Vg + (long)row * 1024 + kv0 + ((c ^ (row & 15)) << 3), (ushort_t*)&Vs[ch * 8]);
        }
        __syncthreads();
        // S = Q K^T : this wave's 32 rows x 128 cols
        f32x4 s_acc[2][8];
        #pragma unroll
        for (int mf = 0; mf < 2; ++mf)
            #pragma unroll
            for (int nf = 0; nf < 8; ++nf) s_acc[mf][nf] = (f32x4){0.f, 0.f, 0.f, 0.f};
        #pragma unroll
        for (int nf = 0; nf < 8; ++nf) {
            #pragma unroll
            for (int kk = 0; kk < 4; ++kk) {
                int row = nf * 16 + l15;
                half8 bf = __builtin_bit_cast(half8, *(const short8*)&Ks[row * 128 + (((kk * 4 + l16) ^ (row & 15)) << 3)]);
                #pragma unroll
                for (int mf = 0; mf < 2; ++mf)
                    s_acc[mf][nf] = __builtin_amdgcn_mfma_f32_16x16x32_f16(qf[mf][kk], bf, s_acc[mf][nf], 0, 0, 0);
            }
        }
        // online softmax (rows = w*32 + mf*16 + l16*4 + j; cols spread over nf and l15)
        #pragma unroll
        for (int mf = 0; mf < 2; ++mf) {
            #pragma unroll
            for (int j = 0; j < 4; ++j) {
                float rmax = -3.0e38f;
                #pragma unroll
                for (int nf = 0; nf < 8; ++nf) rmax = fmaxf(rmax, s_acc[mf][nf][j]);
                #pragma unroll
                for (int off = 1; off < 16; off <<= 1) rmax = fmaxf(rmax, __shfl_xor(rmax, off));
                float m_new = fmaxf(m_run[mf][j], rmax * scale);
                float alpha = __expf(m_run[mf][j] - m_new);
                m_run[mf][j] = m_new;
                float rsum = 0.f;
                #pragma unroll
                for (int nf = 0; nf < 8; ++nf) {
                    float pv = __expf(s_acc[mf][nf][j] * scale - m_new);
                    s_acc[mf][nf][j] = pv;
                    rsum += pv;
                }
                #pragma unroll
                for (int off = 1; off < 16; off <<= 1) rsum += __shfl_xor(rsum, off);
                l_run[mf][j] = l_run[mf][j] * alpha + rsum;
                #pragma unroll
                for (int nf = 0; nf < 8; ++nf) o_acc[mf][nf][j] *= alpha;
            }
        }
        // P -> LDS fp16 (C-layout scatter, swizzled cols)
        #pragma unroll
        for (int mf = 0; mf < 2; ++mf)
            #pragma unroll
            for (int nf = 0; nf < 8; ++nf)
                #pragma unroll
                for (int j = 0; j < 4; ++j) {
                    int row = w * 32 + mf * 16 + l16 * 4 + j;
                    int col = nf * 16 + l15;
                    int sch = (col >> 3) ^ (row & 15);
                    Ps[row * 128 + (sch << 3) + (col & 7)] = (half_t)s_acc[mf][nf][j];
                }
        __syncthreads();
        // O += P V  (A = Ps rows, B = Vs rows = d)
        half8 pf[2][4];
        #pragma unroll
        for (int mf = 0; mf < 2; ++mf)
            #pragma unroll
            for (int kk = 0; kk < 4; ++kk) {
                int row = w * 32 + mf * 16 + l15;
                pf[mf][kk] = __builtin_bit_cast(half8, *(const short8*)&Ps[row * 128 + (((kk * 4 + l16) ^ (row & 15)) << 3)]);
            }
        #pragma unroll
        for (int nf = 0; nf < 8; ++nf) {
            #pragma unroll
            for (int kk = 0; kk < 4; ++kk) {
                int row = nf * 16 + l15;       // d
                half8 bf = __builtin_bit_cast(half8, *(const short8*)&Vs[row * 128 + (((kk * 4 + l16) ^ (row & 15)) << 3)]);
                #pragma unroll
                for (int mf = 0; mf < 2; ++mf)
                    o_acc[mf][nf] = __builtin_amdgcn_mfma_f32_16x16x32_f16(pf[mf][kk], bf, o_acc[mf][nf], 0, 0, 0);
            }
        }
        __syncthreads();                        // protect Ks/Vs/Ps before next stage
    }
    // epilogue: O /= l ; write AO[(b*1024+s)*512 + h*128 + d]
    int b = bh >> 2, h = bh & 3;
    #pragma unroll
    for (int mf = 0; mf < 2; ++mf) {
        #pragma unroll
        for (int nf = 0; nf < 8; ++nf) {
            #pragma unroll
            for (int j = 0; j < 4; ++j) {
                int row = bm + w * 32 + mf * 16 + l16 * 4 + j;
                int col = nf * 16 + l15;
                AO[(long)(b * 1024 + row) * 512 + h * 128 + col] = o_acc[mf][nf][j] / l_run[mf][j];
            }
        }
    }
}

// ---------------- split-K reduction ----------------
template<int KS, bool RELU>
__global__ void reduce_kernel(const float* __restrict__ P, float* __restrict__ out, long MN) {
    long i = ((long)blockIdx.x * 256 + threadIdx.x) * 4;
    if (i >= MN) return;
    f32x4 s = *(const f32x4*)&P[i];
    #pragma unroll
    for (int zz = 1; zz < KS; ++zz) {
        f32x4 t = *(const f32x4*)&P[(size_t)zz * MN + i];
        s += t;
    }
    if constexpr (RELU) {
        s[0] = fmaxf(s[0], 0.f); s[1] = fmaxf(s[1], 0.f);
        s[2] = fmaxf(s[2], 0.f); s[3] = fmaxf(s[3], 0.f);
    }
    *(f32x4*)&out[i] = s;
}

// ---------------- V transpose ----------------
__global__ void transpose_v(const ushort_t* __restrict__ V, ushort_t* __restrict__ Vt) {
    __shared__ ushort_t t[64][72];
    int s0 = blockIdx.x * 64, d0 = blockIdx.y * 64, bh = blockIdx.z;
    const ushort_t* Vb = V + (long)bh * 1024 * 128;
    ushort_t* Vtb = Vt + (long)bh * 128 * 1024;
    int tid = threadIdx.x;
    int r = tid >> 2, g = tid & 3;
    #pragma unroll
    for (int j = 0; j < 16; ++j)
        t[r][g * 16 + j] = Vb[(long)(s0 + r) * 128 + d0 + g * 16 + j];
    __syncthreads();
    #pragma unroll
    for (int j = 0; j < 16; ++j)
        Vtb[(long)(d0 + r) * 1024 + s0 + g * 16 + j] = t[g * 16 + j][r];
}

// ---------------- fused split-K2 reduce + residual + LayerNorm (rows of 512) ----------------
__global__ void reduce2_ln_kernel(const float* __restrict__ P, long MN,
                                  const float* __restrict__ X,
                                  const float* __restrict__ g, const float* __restrict__ b,
                                  float* __restrict__ out) {
    long row = (long)blockIdx.x * 4 + (threadIdx.x >> 6);
    int lane = threadIdx.x & 63;
    long base = row * 512 + lane * 8;
    f32x4 p0 = *(const f32x4*)&P[base],      p1 = *(const f32x4*)&P[base + 4];
    f32x4 q0 = *(const f32x4*)&P[MN + base], q1 = *(const f32x4*)&P[MN + base + 4];
    f32x4 x0 = *(const f32x4*)&X[base],      x1 = *(const f32x4*)&X[base + 4];
    float y[8];
    #pragma unroll
    for (int j = 0; j < 4; ++j) {
        y[j]     = (p0[j] + q0[j]) + x0[j];
        y[j + 4] = (p1[j] + q1[j]) + x1[j];
    }
    float s = 0.f;
    #pragma unroll
    for (int j = 0; j < 8; ++j) s += y[j];
    #pragma unroll
    for (int off = 32; off > 0; off >>= 1) s += __shfl_xor(s, off);
    float mu = s * (1.0f / 512.0f);
    float vs = 0.f;
    #pragma unroll
    for (int j = 0; j < 8; ++j) { float d = y[j] - mu; vs += d * d; }
    #pragma unroll
    for (int off = 32; off > 0; off >>= 1) vs += __shfl_xor(vs, off);
    float r = rsqrtf(vs * (1.0f / 512.0f) + 1e-5f);
    f32x4 w0 = *(const f32x4*)&g[lane * 8], w1 = *(const f32x4*)&g[lane * 8 + 4];
    f32x4 b0 = *(const f32x4*)&b[lane * 8], b1 = *(const f32x4*)&b[lane * 8 + 4];
    f32x4 r0, r1;
    #pragma unroll
    for (int j = 0; j < 4; ++j) {
        r0[j] = (y[j] - mu) * r * w0[j] + b0[j];
        r1[j] = (y[j + 4] - mu) * r * w1[j] + b1[j];
    }
    *(f32x4*)&out[base] = r0;
    *(f32x4*)&out[base + 4] = r1;
}

// ---------------- launch ----------------
extern "C" void kernel_launch(void* const* d_in, const int* in_sizes, int n_in,
                              void* d_out, int out_size, void* d_ws, size_t ws_size,
                              hipStream_t stream) {
    const float* x         = (const float*)d_in[0];
    const float* k1_base   = (const float*)d_in[1];
    const float* k1_spline = (const float*)d_in[2];
    const float* k2_base   = (const float*)d_in[3];
    const float* k2_spline = (const float*)d_in[4];
    const float* q_base    = (const float*)d_in[5];
    const float* q_spline  = (const float*)d_in[6];
    const float* k_base    = (const float*)d_in[7];
    const float* k_spline  = (const float*)d_in[8];
    const float* v_base    = (const float*)d_in[9];
    const float* v_spline  = (const float*)d_in[10];
    const float* o_base    = (const float*)d_in[11];
    const float* o_spline  = (const float*)d_in[12];
    const float* ln_w      = (const float*)d_in[13];
    const float* ln_b      = (const float*)d_in[14];
    float* out = (float*)d_out;

    constexpr int Dm = 512, HD = 1024, NR = 8192;
    constexpr int K1 = 9 * Dm;   // 4608
    constexpr int K2 = 9 * HD;   // 9216
    constexpr size_t MB = 1024 * 1024;

    char* p = (char*)d_ws;
    size_t off = 0;
    auto take = [&](size_t bytes) -> char* {
        char* r = p + off;
        off += (bytes + 255) & ~(size_t)255;
        return r;
    };
    half_t* W1hi = (half_t*)take((size_t)HD * K1 * 2);
    half_t* W2hi = (half_t*)take((size_t)Dm * K2 * 2);
    half_t* Wqhi = (half_t*)take((size_t)3 * Dm * K1 * 2);
    half_t* Wohi = (half_t*)take((size_t)Dm * K1 * 2);
    half_t* W1lo = (half_t*)take((size_t)HD * K1 * 2);
    half_t* W2lo = (half_t*)take((size_t)Dm * K2 * 2);
    half_t* Wqlo = (half_t*)take((size_t)3 * Dm * K1 * 2);
    half_t* Wolo = (half_t*)take((size_t)Dm * K1 * 2);
    char*   A    = take((size_t)152 * MB);
    (void)ws_size; (void)in_sizes; (void)n_in; (void)out_size;

    // arena phase map (MB):
    // A: E1 @0..72 | H1 fp32 @72..104 (direct ReLU epilogue)
    // B: E2c @0..72 | H1 @72..104 | P2 @104..136 (4x8) | H2 @136..152
    // C: E3 @0..72 | Q @72..80 K @80..88 V @88..96 | H2 @136..152
    // D: Vt @96..104 (V dead) | flash: reads Q/K/Vt, writes AO fp32 @104..120
    // E: E4 @0..72 | P3 @120..152 (2x16) | fused reduce2+LN reads P3 directly
    half_t* E1   = (half_t*)(A);
    float*  H1   = (float*)(A + 72 * MB);
    half_t* E2   = (half_t*)(A);
    float*  P2   = (float*)(A + 104 * MB);
    float*  H2   = (float*)(A + 136 * MB);
    half_t* E3   = (half_t*)(A);
    half_t* Qb   = (half_t*)(A + 72 * MB);
    half_t* Kb   = (half_t*)(A + 80 * MB);
    half_t* Vb   = (half_t*)(A + 88 * MB);
    half_t* Vt   = (half_t*)(A + 96 * MB);
    float*  AO   = (float*)(A + 104 * MB);
    half_t* E4   = (half_t*)(A);
    float*  P3   = (float*)(A + 120 * MB);

    pack_kernel<Dm><<<(HD * Dm) / 256, 256, 0, stream>>>(k1_base, k1_spline, W1hi, W1lo, HD);
    pack_kernel<HD><<<(Dm * HD) / 256, 256, 0, stream>>>(k2_base, k2_spline, W2hi, W2lo, Dm);
    pack_kernel<Dm><<<(Dm * Dm) / 256, 256, 0, stream>>>(q_base, q_spline, Wqhi, Wqlo, Dm);
    pack_kernel<Dm><<<(Dm * Dm) / 256, 256, 0, stream>>>(k_base, k_spline, Wqhi + (size_t)Dm * K1, Wqlo + (size_t)Dm * K1, Dm);
    pack_kernel<Dm><<<(Dm * Dm) / 256, 256, 0, stream>>>(v_base, v_spline, Wqhi + (size_t)2 * Dm * K1, Wqlo + (size_t)2 * Dm * K1, Dm);
    pack_kernel<Dm><<<(Dm * Dm) / 256, 256, 0, stream>>>(o_base, o_spline, Wohi, Wolo, Dm);

    // KAN1: hi+lo serial, direct ReLU epilogue, grid 64x8 = 512
    expand_kernel<Dm><<<(NR * Dm) / 256, 256, 0, stream>>>(x, E1, NR);
    gemm_w<EPI_RELU, 2, 1><<<dim3(NR / 128, HD / 128, 1), 256, 0, stream>>>(
        (const ushort_t*)E1, (const ushort_t*)W1hi, (const ushort_t*)W1lo,
        H1, nullptr, nullptr, nullptr, nullptr, NR, HD, K1);

    // KAN2 (2 M-chunks, hi+lo, KSPLIT=4): grid 32x4x4 = 512
    for (int c = 0; c < 2; ++c) {
        expand_kernel<HD><<<(4096 * HD) / 256, 256, 0, stream>>>(H1 + (size_t)c * 4096 * HD, E2, 4096);
        gemm_w<EPI_PART, 2, 4><<<dim3(4096 / 128, Dm / 128, 4), 256, 0, stream>>>(
            (const ushort_t*)E2, (const ushort_t*)W2hi, (const ushort_t*)W2lo,
            nullptr, P2, nullptr, nullptr, nullptr, 4096, Dm, K2);
        reduce_kernel<4, false><<<(4096 * Dm) / 1024, 256, 0, stream>>>(P2, H2 + (size_t)c * 4096 * Dm, (long)4096 * Dm);
    }

    // QKV: hi-only single pass, direct scatter, grid 64x12 = 768 (3/CU)
    expand_kernel<Dm><<<(NR * Dm) / 256, 256, 0, stream>>>(H2, E3, NR);
    gemm_w<EPI_QKV, 1, 1><<<dim3(NR / 128, (3 * Dm) / 128, 1), 256, 0, stream>>>(
        (const ushort_t*)E3, (const ushort_t*)Wqhi, (const ushort_t*)Wqlo,
        nullptr, nullptr, Qb, Kb, Vb, NR, 3 * Dm, K1);

    // attention: Vt transpose then one fused flash dispatch (grid 8x32 = 256, 1/CU)
    transpose_v<<<dim3(16, 2, 32), 256, 0, stream>>>((const ushort_t*)Vb, (ushort_t*)Vt);
    flash_attn<<<dim3(8, 32), 256, 0, stream>>>(
        (const ushort_t*)Qb, (const ushort_t*)Kb, (const ushort_t*)Vt, AO,
        0.08838834764831845f);

    // O-proj: hi-only, KSPLIT=2, grid 64x4x2 = 512; fused reduce2 + residual + LN
    expand_kernel<Dm><<<(NR * Dm) / 256, 256, 0, stream>>>(AO, E4, NR);
    gemm_w<EPI_PART, 1, 2><<<dim3(NR / 128, Dm / 128, 2), 256, 0, stream>>>(
        (const ushort_t*)E4, (const ushort_t*)Wohi, (const ushort_t*)Wolo,
        nullptr, P3, nullptr, nullptr, nullptr, NR, Dm, K1);
    reduce2_ln_kernel<<<NR / 4, 256, 0, stream>>>(P3, (long)NR * Dm, x, ln_w, ln_b, out);
}